// Round 1
// 1955.915 us; speedup vs baseline: 1.5004x; 1.5004x over previous
//
#include <hip/hip_runtime.h>
#include <stdint.h>

// Problem dims (fixed)
#define Bq 8
#define Lq 4096
#define Dq 1024
#define Hq 64
#define Mq (Bq*Lq)   // 32768 rows

typedef short bf16x8 __attribute__((ext_vector_type(8)));  // 8 bf16 in 4 VGPRs
typedef float f32x4  __attribute__((ext_vector_type(4)));

__device__ __forceinline__ float b2f(unsigned short u) {
  union { unsigned int i; float f; } v; v.i = ((unsigned int)u) << 16; return v.f;
}
__device__ __forceinline__ unsigned short f2b(float f) {
  union { float f; unsigned int i; } v; v.f = f;
  unsigned int r = v.i + 0x7fffu + ((v.i >> 16) & 1u);  // RNE
  return (unsigned short)(r >> 16);
}
__device__ __forceinline__ bf16x8 pack8(float4 a, float4 b) {
  bf16x8 r;
  r[0] = (short)f2b(a.x); r[1] = (short)f2b(a.y); r[2] = (short)f2b(a.z); r[3] = (short)f2b(a.w);
  r[4] = (short)f2b(b.x); r[5] = (short)f2b(b.y); r[6] = (short)f2b(b.z); r[7] = (short)f2b(b.w);
  return r;
}

// ---------------- dtype classifier: is this buffer bf16 (1) or f32 (0)? ----------------
__global__ void classify_kernel(const unsigned short* __restrict__ w, unsigned int* flag) {
  __shared__ unsigned int s_nz, s_ib;
  if (threadIdx.x == 0) { s_nz = 0; s_ib = 0; }
  __syncthreads();
  unsigned int nz = 0, ib = 0;
  for (int i = threadIdx.x; i < 8192; i += 256) {
    unsigned short u = w[2 * i];
    if (u) {
      nz++;
      unsigned int e = (u >> 7) & 0xFFu;
      if (e >= 0x31u && e <= 0x9Du) ib++;
    }
  }
  atomicAdd(&s_nz, nz); atomicAdd(&s_ib, ib);
  __syncthreads();
  if (threadIdx.x == 0) *flag = (s_nz > 0 && 4u * s_ib >= 3u * s_nz) ? 1u : 0u;
}

// ---------------- ws-too-small sentinel ----------------
__global__ void sentinel_kernel(unsigned short* out, int n) {
  int i = blockIdx.x * 256 + threadIdx.x;
  if (i < n) out[i] = 0x447A;  // bf16 1000.0
}

// ---------------- LayerNorm: one block (256 thr) per row of 1024 ----------------
__global__ void ln_kernel(const void* __restrict__ xv,
                          const void* __restrict__ gv,
                          const void* __restrict__ bev,
                          unsigned short* __restrict__ xn,
                          const unsigned int* __restrict__ flagp) {
  const int isbf = (int)*flagp;
  const int row = blockIdx.x;
  const int t = threadIdx.x;
  const size_t base = (size_t)row * Dq;
  float v0, v1, v2, v3, g0, g1, g2, g3, e0, e1, e2, e3;
  if (isbf) {
    ushort4 u  = *(const ushort4*)((const unsigned short*)xv + base + t * 4);
    ushort4 g  = *(const ushort4*)((const unsigned short*)gv + t * 4);
    ushort4 be = *(const ushort4*)((const unsigned short*)bev + t * 4);
    v0 = b2f(u.x); v1 = b2f(u.y); v2 = b2f(u.z); v3 = b2f(u.w);
    g0 = b2f(g.x); g1 = b2f(g.y); g2 = b2f(g.z); g3 = b2f(g.w);
    e0 = b2f(be.x); e1 = b2f(be.y); e2 = b2f(be.z); e3 = b2f(be.w);
  } else {
    float4 u  = *(const float4*)((const float*)xv + base + t * 4);
    float4 g  = *(const float4*)((const float*)gv + t * 4);
    float4 be = *(const float4*)((const float*)bev + t * 4);
    v0 = u.x; v1 = u.y; v2 = u.z; v3 = u.w;
    g0 = g.x; g1 = g.y; g2 = g.z; g3 = g.w;
    e0 = be.x; e1 = be.y; e2 = be.z; e3 = be.w;
  }
  float s  = v0 + v1 + v2 + v3;
  float ss = v0*v0 + v1*v1 + v2*v2 + v3*v3;
#pragma unroll
  for (int off = 32; off >= 1; off >>= 1) {
    s  += __shfl_xor(s,  off, 64);
    ss += __shfl_xor(ss, off, 64);
  }
  __shared__ float sb[8];
  const int w = t >> 6, lane = t & 63;
  if (lane == 0) { sb[w] = s; sb[4 + w] = ss; }
  __syncthreads();
  s  = sb[0] + sb[1] + sb[2] + sb[3];
  ss = sb[4] + sb[5] + sb[6] + sb[7];
  const float mu   = s * (1.0f / Dq);
  const float var  = ss * (1.0f / Dq) - mu * mu;
  const float rstd = rsqrtf(var + 1e-5f);
  ushort4 o;
  o.x = f2b((v0 - mu) * rstd * g0 + e0);
  o.y = f2b((v1 - mu) * rstd * g1 + e1);
  o.z = f2b((v2 - mu) * rstd * g2 + e2);
  o.w = f2b((v3 - mu) * rstd * g3 + e3);
  *(ushort4*)(xn + base + t * 4) = o;
}

// ---------------- MFMA GEMM: out[m,n] = (sum_k A[m,k]*W[n,k] + bias[n])*scale (+resid) ----
// out_mode: 0 = bf16, 1 = f32, 2 = follow flag (bf16 if isbf else f32).
// out_layout: 0 = row-major [M,N]; 1 = qkv [B,H,L,16]; 2 = gate [B,H,L].
__global__ void gemm_bt(const unsigned short* __restrict__ A,
                        const void* __restrict__ Wv,
                        const void* __restrict__ biasv,
                        const void* __restrict__ residv,
                        void* __restrict__ out,
                        int N, int K, float scale, int out_mode, int out_layout,
                        const unsigned int* __restrict__ flagp) {
  __shared__ unsigned short smA[128 * 32];
  __shared__ unsigned short smB[128 * 32];
  const int isbf = (int)*flagp;
  const int tid  = threadIdx.x;
  const int w    = tid >> 6;
  const int lane = tid & 63;
  const int wm   = w >> 1;
  const int wn   = w & 1;
  const int row0 = blockIdx.x * 128;
  const int col0 = blockIdx.y * 128;

  const int c0 = tid, c1 = tid + 256;
  const int ar0 = row0 + (c0 >> 2), ak0 = (c0 & 3) * 8;
  const int ar1 = row0 + (c1 >> 2), ak1 = (c1 & 3) * 8;
  int br0 = col0 + (c0 >> 2), bk0 = (c0 & 3) * 8;
  int br1 = col0 + (c1 >> 2), bk1 = (c1 & 3) * 8;
  if (br0 >= N) br0 = N - 1;
  if (br1 >= N) br1 = N - 1;
  const size_t aro0 = (size_t)ar0 * K + ak0;
  const size_t aro1 = (size_t)ar1 * K + ak1;
  const size_t bro0 = (size_t)br0 * K + bk0;
  const size_t bro1 = (size_t)br1 * K + bk1;

  f32x4 acc[4][4];
#pragma unroll
  for (int i = 0; i < 4; ++i)
#pragma unroll
    for (int j = 0; j < 4; ++j) acc[i][j] = (f32x4){0.f, 0.f, 0.f, 0.f};

  const int mrow = lane & 15;
  const int kq8  = (lane >> 4) * 8;

  for (int k0 = 0; k0 < K; k0 += 32) {
    bf16x8 ta0 = *(const bf16x8*)(A + aro0 + k0);
    bf16x8 ta1 = *(const bf16x8*)(A + aro1 + k0);
    bf16x8 tb0, tb1;
    if (isbf) {
      const unsigned short* W = (const unsigned short*)Wv;
      tb0 = *(const bf16x8*)(W + bro0 + k0);
      tb1 = *(const bf16x8*)(W + bro1 + k0);
    } else {
      const float* W = (const float*)Wv;
      float4 w00 = *(const float4*)(W + bro0 + k0);
      float4 w01 = *(const float4*)(W + bro0 + k0 + 4);
      float4 w10 = *(const float4*)(W + bro1 + k0);
      float4 w11 = *(const float4*)(W + bro1 + k0 + 4);
      tb0 = pack8(w00, w01);
      tb1 = pack8(w10, w11);
    }
    __syncthreads();
    *(bf16x8*)(smA + c0 * 8) = ta0;
    *(bf16x8*)(smA + c1 * 8) = ta1;
    *(bf16x8*)(smB + c0 * 8) = tb0;
    *(bf16x8*)(smB + c1 * 8) = tb1;
    __syncthreads();
    bf16x8 a[4], bb[4];
#pragma unroll
    for (int mt = 0; mt < 4; ++mt)
      a[mt] = *(const bf16x8*)(smA + (wm * 64 + mt * 16 + mrow) * 32 + kq8);
#pragma unroll
    for (int nt = 0; nt < 4; ++nt)
      bb[nt] = *(const bf16x8*)(smB + (wn * 64 + nt * 16 + mrow) * 32 + kq8);
#pragma unroll
    for (int mt = 0; mt < 4; ++mt)
#pragma unroll
      for (int nt = 0; nt < 4; ++nt)
        acc[mt][nt] = __builtin_amdgcn_mfma_f32_16x16x32_bf16(a[mt], bb[nt], acc[mt][nt], 0, 0, 0);
  }

  // epilogue: C/D layout col=lane&15, row=(lane>>4)*4+reg
  const int colL = lane & 15;
  const int rq   = lane >> 4;
  const int wf32 = (out_mode == 1) || (out_mode == 2 && !isbf);
#pragma unroll
  for (int nt = 0; nt < 4; ++nt) {
    const int col = col0 + wn * 64 + nt * 16 + colL;
    if (col >= N) continue;
    const float bv = isbf ? b2f(((const unsigned short*)biasv)[col])
                          : ((const float*)biasv)[col];
#pragma unroll
    for (int mt = 0; mt < 4; ++mt) {
      const int rowb = row0 + wm * 64 + mt * 16 + rq * 4;
#pragma unroll
      for (int r = 0; r < 4; ++r) {
        const int row = rowb + r;
        size_t idx;
        if (out_layout == 1) {
          const int bb2 = row >> 12, t = row & 4095;           // L=4096
          idx = ((((size_t)bb2 * Hq + (col >> 4)) << 12) + t) * 16 + (col & 15);
        } else if (out_layout == 2) {
          const int bb2 = row >> 12, t = row & 4095;
          idx = (((size_t)bb2 * Hq + col) << 12) + t;
        } else {
          idx = (size_t)row * N + col;
        }
        float val = (acc[mt][nt][r] + bv) * scale;
        if (residv) {
          const size_t ridx = (size_t)row * N + col;           // resid always [M,N]
          val += isbf ? b2f(((const unsigned short*)residv)[ridx])
                      : ((const float*)residv)[ridx];
        }
        if (wf32) ((float*)out)[idx] = val;
        else ((unsigned short*)out)[idx] = f2b(val);
      }
    }
  }
}

// ---------------- Sequential mLSTM scan: one wave per (b,h), tiled+prefetched ----------
// q/k/v in [B,H,L,16] bf16; gates in [B,H,L] f32; h out in standard [B,L,D] bf16.
// lane: e = lane&15 (k/output index), d = (lane>>4)*4 + r (v/q index); C[d][e] 4/lane.
#define TS 64   // timesteps per tile (= lanes: 1 step staged per lane)

__device__ __forceinline__ void deposit16(float* __restrict__ dstrow, int xw,
                                          bf16x8 lo, bf16x8 hi) {
  float t[16];
#pragma unroll
  for (int j = 0; j < 8; ++j) t[j] = b2f((unsigned short)lo[j]);
#pragma unroll
  for (int j = 0; j < 8; ++j) t[8 + j] = b2f((unsigned short)hi[j]);
#pragma unroll
  for (int qd = 0; qd < 4; ++qd) {
    *(float4*)(dstrow + ((qd << 2) ^ xw)) =
        make_float4(t[qd * 4], t[qd * 4 + 1], t[qd * 4 + 2], t[qd * 4 + 3]);
  }
}

__global__ void __launch_bounds__(64, 1)
scan_kernel(const unsigned short* __restrict__ q,
            const unsigned short* __restrict__ k,
            const unsigned short* __restrict__ v,
            const float* __restrict__ itg,
            const float* __restrict__ ftg,
            unsigned short* __restrict__ hout) {
  __shared__ float sk[TS * 16], sq[TS * 16], sv[TS * 16], sg[2 * TS];
  const int bh = blockIdx.x;
  const int b  = bh >> 6;
  const int h  = bh & 63;
  const int lane = threadIdx.x;
  const int e  = lane & 15;
  const int dg = lane >> 4;
  const int d0 = dg * 4;
  const size_t qkvb = (size_t)bh * Lq * 16;
  const size_t gb   = (size_t)bh * Lq;
  const size_t ob   = (size_t)b * Lq * Dq + (size_t)h * 16;

  float C0 = 0, C1 = 0, C2 = 0, C3 = 0;
  float n0 = 0, n1 = 0, n2 = 0, n3 = 0;
  float m = 0.f;

  // prefetch registers: one timestep (16 bf16 per tensor) per lane
  bf16x8 rk0, rk1, rq0, rq1, rv0, rv1;
  float rit, rft;
  {
    const unsigned short* kp = k + qkvb + (size_t)lane * 16;
    const unsigned short* qp = q + qkvb + (size_t)lane * 16;
    const unsigned short* vp = v + qkvb + (size_t)lane * 16;
    rk0 = *(const bf16x8*)kp; rk1 = *(const bf16x8*)(kp + 8);
    rq0 = *(const bf16x8*)qp; rq1 = *(const bf16x8*)(qp + 8);
    rv0 = *(const bf16x8*)vp; rv1 = *(const bf16x8*)(vp + 8);
    rit = itg[gb + lane]; rft = ftg[gb + lane];
  }

  const int xw = ((lane >> 1) & 3) << 2;  // write swizzle (quad XOR) for this lane's row
  const int NT = Lq / TS;
  for (int c = 0; c < NT; ++c) {
    // deposit the prefetched tile (f32, quad-swizzled) into LDS
    deposit16(sk + lane * 16, xw, rk0, rk1);
    deposit16(sq + lane * 16, xw, rq0, rq1);
    deposit16(sv + lane * 16, xw, rv0, rv1);
    sg[lane] = rit; sg[TS + lane] = rft;
    // issue next tile's global loads (full compute phase to land)
    if (c + 1 < NT) {
      const size_t off = qkvb + ((size_t)(c + 1) * TS + lane) * 16;
      const unsigned short* kp = k + off;
      const unsigned short* qp = q + off;
      const unsigned short* vp = v + off;
      rk0 = *(const bf16x8*)kp; rk1 = *(const bf16x8*)(kp + 8);
      rq0 = *(const bf16x8*)qp; rq1 = *(const bf16x8*)(qp + 8);
      rv0 = *(const bf16x8*)vp; rv1 = *(const bf16x8*)(vp + 8);
      rit = itg[gb + (size_t)(c + 1) * TS + lane];
      rft = ftg[gb + (size_t)(c + 1) * TS + lane];
    }
    // 64 sequential timesteps from LDS (single wave: no barriers; DS in-order)
#pragma unroll 4
    for (int s = 0; s < TS; ++s) {
      const int x = ((s >> 1) & 3) << 2;
      const float* kr = sk + s * 16;
      const float* qr = sq + s * 16;
      const float* vr = sv + s * 16;
      const float itc = sg[s];
      const float ftc = sg[TS + s];
      const float ke  = kr[e ^ x];
      const float4 kq4 = *(const float4*)(kr + (d0 ^ x));
      const float4 qq4 = *(const float4*)(qr + (d0 ^ x));
      const float4 vq4 = *(const float4*)(vr + (d0 ^ x));
      const float fm = ftc + m;
      const float mn = fmaxf(fm, itc);
      const float fg = __expf(fm - mn);   // <= 1
      const float ig = __expf(itc - mn);  // <= 1
      m = mn;
      const float a = ig * ke;
      C0 = fmaf(fg, C0, a * vq4.x);
      C1 = fmaf(fg, C1, a * vq4.y);
      C2 = fmaf(fg, C2, a * vq4.z);
      C3 = fmaf(fg, C3, a * vq4.w);
      n0 = fmaf(fg, n0, ig * kq4.x);
      n1 = fmaf(fg, n1, ig * kq4.y);
      n2 = fmaf(fg, n2, ig * kq4.z);
      n3 = fmaf(fg, n3, ig * kq4.w);
      float cq = fmaf(C3, qq4.w, fmaf(C2, qq4.z, fmaf(C1, qq4.y, C0 * qq4.x)));
      float dn = fmaf(n3, qq4.w, fmaf(n2, qq4.z, fmaf(n1, qq4.y, n0 * qq4.x)));
      cq += __shfl_xor(cq, 16, 64);
      cq += __shfl_xor(cq, 32, 64);
      dn += __shfl_xor(dn, 16, 64);
      dn += __shfl_xor(dn, 32, 64);
      const float denom = fmaxf(fabsf(dn), 1.0f);
      if (dg == 0) hout[ob + (size_t)(c * TS + s) * Dq + e] = f2b(cq / denom);
    }
  }
}

extern "C" void kernel_launch(void* const* d_in, const int* in_sizes, int n_in,
                              void* d_out, int out_size, void* d_ws, size_t ws_size,
                              hipStream_t stream) {
  const void* x     = d_in[0];
  const void* gamma = d_in[1];
  const void* beta  = d_in[2];
  const void* qw    = d_in[3];
  const void* qbv   = d_in[4];
  const void* kw    = d_in[5];
  const void* kbv   = d_in[6];
  const void* vw    = d_in[7];
  const void* vbv   = d_in[8];
  const void* ow    = d_in[9];
  const void* obv   = d_in[10];
  const void* iw    = d_in[11];
  const void* ibv   = d_in[12];
  const void* fw    = d_in[13];
  const void* fbv   = d_in[14];

  const size_t bufBytes = (size_t)Mq * Dq * 2;        // 64 MiB
  const size_t gateBytes = (size_t)Mq * Hq * 4;       // 8 MiB
  const size_t need = 4 * bufBytes + 2 * gateBytes + 4096;
  if (ws_size < need) {   // diagnostic: absmax ~= 1000 signals this branch
    sentinel_kernel<<<(out_size + 255) / 256, 256, 0, stream>>>((unsigned short*)d_out, out_size);
    return;
  }

  char* ws = (char*)d_ws;
  unsigned short* xnb = (unsigned short*)ws; ws += bufBytes;   // reused as hbf
  unsigned short* qbf = (unsigned short*)ws; ws += bufBytes;
  unsigned short* kbf = (unsigned short*)ws; ws += bufBytes;
  unsigned short* vbf = (unsigned short*)ws; ws += bufBytes;
  float* itb = (float*)ws; ws += gateBytes;
  float* ftb = (float*)ws; ws += gateBytes;
  unsigned int* flagp = (unsigned int*)ws;
  unsigned short* hbf = xnb;  // alias: xn dead after the 5 projection GEMMs

  classify_kernel<<<1, 256, 0, stream>>>((const unsigned short*)qw, flagp);
  ln_kernel<<<Mq, 256, 0, stream>>>(x, gamma, beta, xnb, flagp);
  // q/k/v -> [B,H,L,16] bf16 (layout 1); gates -> [B,H,L] f32 (layout 2)
  gemm_bt<<<dim3(Mq / 128, 8), 256, 0, stream>>>(xnb, qw, qbv, nullptr, qbf, Dq, Dq, 1.0f,  0, 1, flagp);
  gemm_bt<<<dim3(Mq / 128, 8), 256, 0, stream>>>(xnb, kw, kbv, nullptr, kbf, Dq, Dq, 0.25f, 0, 1, flagp); // /sqrt(16)
  gemm_bt<<<dim3(Mq / 128, 8), 256, 0, stream>>>(xnb, vw, vbv, nullptr, vbf, Dq, Dq, 1.0f,  0, 1, flagp);
  gemm_bt<<<dim3(Mq / 128, 1), 256, 0, stream>>>(xnb, iw, ibv, nullptr, itb, Hq, Dq, 1.0f,  1, 2, flagp);
  gemm_bt<<<dim3(Mq / 128, 1), 256, 0, stream>>>(xnb, fw, fbv, nullptr, ftb, Hq, Dq, 1.0f,  1, 2, flagp);
  scan_kernel<<<Bq * Hq, 64, 0, stream>>>(qbf, kbf, vbf, itb, ftb, hbf);
  gemm_bt<<<dim3(Mq / 128, 8), 256, 0, stream>>>(hbf, ow, obv, x, d_out, Dq, Dq, 1.0f, 2, 0, flagp);
}

// Round 2
// 1259.713 us; speedup vs baseline: 2.3297x; 1.5527x over previous
//
#include <hip/hip_runtime.h>
#include <stdint.h>

// Problem dims (fixed)
#define Bq 8
#define Lq 4096
#define Dq 1024
#define Hq 64
#define Mq (Bq*Lq)   // 32768 rows
#define CH 64        // scan chunk length
#define NC (Lq/CH)   // 64 chunks per (b,h)
#define TC (Bq*Hq*NC) // 32768 chunk tasks
#define RECF 288     // f32 per chunk record: 256 C + 16 n + Ml + F + pad

typedef short bf16x8 __attribute__((ext_vector_type(8)));  // 8 bf16 in 4 VGPRs
typedef float f32x4  __attribute__((ext_vector_type(4)));

__device__ __forceinline__ float b2f(unsigned short u) {
  union { unsigned int i; float f; } v; v.i = ((unsigned int)u) << 16; return v.f;
}
__device__ __forceinline__ unsigned short f2b(float f) {
  union { float f; unsigned int i; } v; v.f = f;
  unsigned int r = v.i + 0x7fffu + ((v.i >> 16) & 1u);  // RNE
  return (unsigned short)(r >> 16);
}
__device__ __forceinline__ bf16x8 pack8(float4 a, float4 b) {
  bf16x8 r;
  r[0] = (short)f2b(a.x); r[1] = (short)f2b(a.y); r[2] = (short)f2b(a.z); r[3] = (short)f2b(a.w);
  r[4] = (short)f2b(b.x); r[5] = (short)f2b(b.y); r[6] = (short)f2b(b.z); r[7] = (short)f2b(b.w);
  return r;
}

// ---------------- dtype classifier: is this buffer bf16 (1) or f32 (0)? ----------------
__global__ void classify_kernel(const unsigned short* __restrict__ w, unsigned int* flag) {
  __shared__ unsigned int s_nz, s_ib;
  if (threadIdx.x == 0) { s_nz = 0; s_ib = 0; }
  __syncthreads();
  unsigned int nz = 0, ib = 0;
  for (int i = threadIdx.x; i < 8192; i += 256) {
    unsigned short u = w[2 * i];
    if (u) {
      nz++;
      unsigned int e = (u >> 7) & 0xFFu;
      if (e >= 0x31u && e <= 0x9Du) ib++;
    }
  }
  atomicAdd(&s_nz, nz); atomicAdd(&s_ib, ib);
  __syncthreads();
  if (threadIdx.x == 0) *flag = (s_nz > 0 && 4u * s_ib >= 3u * s_nz) ? 1u : 0u;
}

// ---------------- ws-too-small sentinel ----------------
__global__ void sentinel_kernel(unsigned short* out, int n) {
  int i = blockIdx.x * 256 + threadIdx.x;
  if (i < n) out[i] = 0x447A;  // bf16 1000.0
}

// ---------------- LayerNorm: one block (256 thr) per row of 1024 ----------------
__global__ void ln_kernel(const void* __restrict__ xv,
                          const void* __restrict__ gv,
                          const void* __restrict__ bev,
                          unsigned short* __restrict__ xn,
                          const unsigned int* __restrict__ flagp) {
  const int isbf = (int)*flagp;
  const int row = blockIdx.x;
  const int t = threadIdx.x;
  const size_t base = (size_t)row * Dq;
  float v0, v1, v2, v3, g0, g1, g2, g3, e0, e1, e2, e3;
  if (isbf) {
    ushort4 u  = *(const ushort4*)((const unsigned short*)xv + base + t * 4);
    ushort4 g  = *(const ushort4*)((const unsigned short*)gv + t * 4);
    ushort4 be = *(const ushort4*)((const unsigned short*)bev + t * 4);
    v0 = b2f(u.x); v1 = b2f(u.y); v2 = b2f(u.z); v3 = b2f(u.w);
    g0 = b2f(g.x); g1 = b2f(g.y); g2 = b2f(g.z); g3 = b2f(g.w);
    e0 = b2f(be.x); e1 = b2f(be.y); e2 = b2f(be.z); e3 = b2f(be.w);
  } else {
    float4 u  = *(const float4*)((const float*)xv + base + t * 4);
    float4 g  = *(const float4*)((const float*)gv + t * 4);
    float4 be = *(const float4*)((const float*)bev + t * 4);
    v0 = u.x; v1 = u.y; v2 = u.z; v3 = u.w;
    g0 = g.x; g1 = g.y; g2 = g.z; g3 = g.w;
    e0 = be.x; e1 = be.y; e2 = be.z; e3 = be.w;
  }
  float s  = v0 + v1 + v2 + v3;
  float ss = v0*v0 + v1*v1 + v2*v2 + v3*v3;
#pragma unroll
  for (int off = 32; off >= 1; off >>= 1) {
    s  += __shfl_xor(s,  off, 64);
    ss += __shfl_xor(ss, off, 64);
  }
  __shared__ float sb[8];
  const int w = t >> 6, lane = t & 63;
  if (lane == 0) { sb[w] = s; sb[4 + w] = ss; }
  __syncthreads();
  s  = sb[0] + sb[1] + sb[2] + sb[3];
  ss = sb[4] + sb[5] + sb[6] + sb[7];
  const float mu   = s * (1.0f / Dq);
  const float var  = ss * (1.0f / Dq) - mu * mu;
  const float rstd = rsqrtf(var + 1e-5f);
  ushort4 o;
  o.x = f2b((v0 - mu) * rstd * g0 + e0);
  o.y = f2b((v1 - mu) * rstd * g1 + e1);
  o.z = f2b((v2 - mu) * rstd * g2 + e2);
  o.w = f2b((v3 - mu) * rstd * g3 + e3);
  *(ushort4*)(xn + base + t * 4) = o;
}

// ---------------- MFMA GEMM: out[m,n] = (sum_k A[m,k]*W[n,k] + bias[n])*scale (+resid) ----
// out_mode: 0 = bf16, 1 = f32, 2 = follow flag (bf16 if isbf else f32).
// out_layout: 0 = row-major [M,N]; 1 = qkv [B,H,L,16]; 2 = gate [B,H,L].
__global__ void gemm_bt(const unsigned short* __restrict__ A,
                        const void* __restrict__ Wv,
                        const void* __restrict__ biasv,
                        const void* __restrict__ residv,
                        void* __restrict__ out,
                        int N, int K, float scale, int out_mode, int out_layout,
                        const unsigned int* __restrict__ flagp) {
  __shared__ unsigned short smA[128 * 32];
  __shared__ unsigned short smB[128 * 32];
  const int isbf = (int)*flagp;
  const int tid  = threadIdx.x;
  const int w    = tid >> 6;
  const int lane = tid & 63;
  const int wm   = w >> 1;
  const int wn   = w & 1;
  const int row0 = blockIdx.x * 128;
  const int col0 = blockIdx.y * 128;

  const int c0 = tid, c1 = tid + 256;
  const int ar0 = row0 + (c0 >> 2), ak0 = (c0 & 3) * 8;
  const int ar1 = row0 + (c1 >> 2), ak1 = (c1 & 3) * 8;
  int br0 = col0 + (c0 >> 2), bk0 = (c0 & 3) * 8;
  int br1 = col0 + (c1 >> 2), bk1 = (c1 & 3) * 8;
  if (br0 >= N) br0 = N - 1;
  if (br1 >= N) br1 = N - 1;
  const size_t aro0 = (size_t)ar0 * K + ak0;
  const size_t aro1 = (size_t)ar1 * K + ak1;
  const size_t bro0 = (size_t)br0 * K + bk0;
  const size_t bro1 = (size_t)br1 * K + bk1;

  f32x4 acc[4][4];
#pragma unroll
  for (int i = 0; i < 4; ++i)
#pragma unroll
    for (int j = 0; j < 4; ++j) acc[i][j] = (f32x4){0.f, 0.f, 0.f, 0.f};

  const int mrow = lane & 15;
  const int kq8  = (lane >> 4) * 8;

  for (int k0 = 0; k0 < K; k0 += 32) {
    bf16x8 ta0 = *(const bf16x8*)(A + aro0 + k0);
    bf16x8 ta1 = *(const bf16x8*)(A + aro1 + k0);
    bf16x8 tb0, tb1;
    if (isbf) {
      const unsigned short* W = (const unsigned short*)Wv;
      tb0 = *(const bf16x8*)(W + bro0 + k0);
      tb1 = *(const bf16x8*)(W + bro1 + k0);
    } else {
      const float* W = (const float*)Wv;
      float4 w00 = *(const float4*)(W + bro0 + k0);
      float4 w01 = *(const float4*)(W + bro0 + k0 + 4);
      float4 w10 = *(const float4*)(W + bro1 + k0);
      float4 w11 = *(const float4*)(W + bro1 + k0 + 4);
      tb0 = pack8(w00, w01);
      tb1 = pack8(w10, w11);
    }
    __syncthreads();
    *(bf16x8*)(smA + c0 * 8) = ta0;
    *(bf16x8*)(smA + c1 * 8) = ta1;
    *(bf16x8*)(smB + c0 * 8) = tb0;
    *(bf16x8*)(smB + c1 * 8) = tb1;
    __syncthreads();
    bf16x8 a[4], bb[4];
#pragma unroll
    for (int mt = 0; mt < 4; ++mt)
      a[mt] = *(const bf16x8*)(smA + (wm * 64 + mt * 16 + mrow) * 32 + kq8);
#pragma unroll
    for (int nt = 0; nt < 4; ++nt)
      bb[nt] = *(const bf16x8*)(smB + (wn * 64 + nt * 16 + mrow) * 32 + kq8);
#pragma unroll
    for (int mt = 0; mt < 4; ++mt)
#pragma unroll
      for (int nt = 0; nt < 4; ++nt)
        acc[mt][nt] = __builtin_amdgcn_mfma_f32_16x16x32_bf16(a[mt], bb[nt], acc[mt][nt], 0, 0, 0);
  }

  // epilogue: C/D layout col=lane&15, row=(lane>>4)*4+reg
  const int colL = lane & 15;
  const int rq   = lane >> 4;
  const int wf32 = (out_mode == 1) || (out_mode == 2 && !isbf);
#pragma unroll
  for (int nt = 0; nt < 4; ++nt) {
    const int col = col0 + wn * 64 + nt * 16 + colL;
    if (col >= N) continue;
    const float bv = isbf ? b2f(((const unsigned short*)biasv)[col])
                          : ((const float*)biasv)[col];
#pragma unroll
    for (int mt = 0; mt < 4; ++mt) {
      const int rowb = row0 + wm * 64 + mt * 16 + rq * 4;
#pragma unroll
      for (int r = 0; r < 4; ++r) {
        const int row = rowb + r;
        size_t idx;
        if (out_layout == 1) {
          const int bb2 = row >> 12, t = row & 4095;           // L=4096
          idx = ((((size_t)bb2 * Hq + (col >> 4)) << 12) + t) * 16 + (col & 15);
        } else if (out_layout == 2) {
          const int bb2 = row >> 12, t = row & 4095;
          idx = (((size_t)bb2 * Hq + col) << 12) + t;
        } else {
          idx = (size_t)row * N + col;
        }
        float val = (acc[mt][nt][r] + bv) * scale;
        if (residv) {
          const size_t ridx = (size_t)row * N + col;           // resid always [M,N]
          val += isbf ? b2f(((const unsigned short*)residv)[ridx])
                      : ((const float*)residv)[ridx];
        }
        if (wf32) ((float*)out)[idx] = val;
        else ((unsigned short*)out)[idx] = f2b(val);
      }
    }
  }
}

// ---------------- shared helper: bf16x16 row -> f32 LDS row with quad swizzle ----------
__device__ __forceinline__ void deposit16(float* __restrict__ dstrow, int xw,
                                          bf16x8 lo, bf16x8 hi) {
  float t[16];
#pragma unroll
  for (int j = 0; j < 8; ++j) t[j] = b2f((unsigned short)lo[j]);
#pragma unroll
  for (int j = 0; j < 8; ++j) t[8 + j] = b2f((unsigned short)hi[j]);
#pragma unroll
  for (int qd = 0; qd < 4; ++qd) {
    *(float4*)(dstrow + ((qd << 2) ^ xw)) =
        make_float4(t[qd * 4], t[qd * 4 + 1], t[qd * 4 + 2], t[qd * 4 + 3]);
  }
}

// =================== chunked-parallel mLSTM scan ===================
// Decomposition: F_t = prefix-sum(f), w_s = i_s - F_s, m_t = F_t + max(m_in, max_{s<=t} w_s)
//   C_t = exp(m_in + F_t - m_t) C_in + exp(F_t - m_t) sum_{s<=t} exp(w_s) v_s k_s^T
// Record layout (f32, per chunk, stride RECF): [e*16+d] C_{d,e}; [256+d] n_d; [272] Ml/m_in; [273] F.

// Pass 1: per-chunk summaries (fully parallel, one wave per chunk)
__global__ void __launch_bounds__(64, 1)
summary_kernel(const unsigned short* __restrict__ k,
               const unsigned short* __restrict__ v,
               const float* __restrict__ itg,
               const float* __restrict__ ftg,
               float* __restrict__ sum) {
  __shared__ float sk[CH * 16], sv[CH * 16], sp[CH];
  const int bid = blockIdx.x;
  const int bh  = bid >> 6;            // NC == 64
  const int c   = bid & 63;
  const int lane = threadIdx.x;
  const int e  = lane & 15;
  const int dg = lane >> 4;
  const int d0 = dg * 4;
  const size_t qkvb = ((size_t)bh * Lq + (size_t)c * CH) * 16;
  const size_t gb   = (size_t)bh * Lq + (size_t)c * CH;

  // per-lane gates; lane index == local timestep
  float fv = ftg[gb + lane];
  float iv = itg[gb + lane];
  // inclusive prefix-sum of f across the wave
  float F = fv;
#pragma unroll
  for (int off = 1; off < 64; off <<= 1) {
    float tt = __shfl_up(F, off, 64);
    if (lane >= off) F += tt;
  }
  float wv = iv - F;
  float Ml = wv;
#pragma unroll
  for (int off = 1; off < 64; off <<= 1)
    Ml = fmaxf(Ml, __shfl_xor(Ml, off, 64));
  const float Ftot = __shfl(F, 63, 64);

  const int xw = ((lane >> 1) & 3) << 2;
  {
    const unsigned short* kp = k + qkvb + (size_t)lane * 16;
    const unsigned short* vp = v + qkvb + (size_t)lane * 16;
    bf16x8 a0 = *(const bf16x8*)kp, a1 = *(const bf16x8*)(kp + 8);
    bf16x8 b0 = *(const bf16x8*)vp, b1 = *(const bf16x8*)(vp + 8);
    deposit16(sk + lane * 16, xw, a0, a1);
    deposit16(sv + lane * 16, xw, b0, b1);
    sp[lane] = __expf(wv - Ml);   // p_s in (0,1]
  }
  float C0 = 0, C1 = 0, C2 = 0, C3 = 0;
  float g0 = 0, g1 = 0, g2 = 0, g3 = 0;
#pragma unroll 4
  for (int s = 0; s < CH; ++s) {
    const int x = ((s >> 1) & 3) << 2;
    const float* kr = sk + s * 16;
    const float* vr = sv + s * 16;
    const float p  = sp[s];
    const float ke = kr[e ^ x];
    const float4 kq = *(const float4*)(kr + (d0 ^ x));
    const float4 vq = *(const float4*)(vr + (d0 ^ x));
    const float a = p * ke;
    C0 = fmaf(a, vq.x, C0); C1 = fmaf(a, vq.y, C1);
    C2 = fmaf(a, vq.z, C2); C3 = fmaf(a, vq.w, C3);
    g0 = fmaf(p, kq.x, g0); g1 = fmaf(p, kq.y, g1);
    g2 = fmaf(p, kq.z, g2); g3 = fmaf(p, kq.w, g3);
  }
  float* rec = sum + (size_t)bid * RECF;
  *(float4*)(rec + e * 16 + d0) = make_float4(C0, C1, C2, C3);
  if (e == 0) *(float4*)(rec + 256 + d0) = make_float4(g0, g1, g2, g3);
  if (lane == 0) { rec[272] = Ml; rec[273] = Ftot; }
}

// Pass 2: sequential combine over chunks per (b,h); rewrites each record with the
// INCOMING (chunk-start) state in place.
__global__ void __launch_bounds__(64, 1)
combine_kernel(float* __restrict__ sum) {
  const int bh = blockIdx.x;
  const int lane = threadIdx.x;
  float* base = sum + (size_t)bh * NC * RECF;
  float4 Sc = make_float4(0.f, 0.f, 0.f, 0.f);
  float Sn = 0.f;
  float m = 0.f;
  // prefetch chunk 0
  float4 G = *(float4*)(base + lane * 4);
  float gn = (lane < 16) ? base[256 + lane] : 0.f;
  float Ml = base[272], F = base[273];
  for (int c = 0; c < NC; ++c) {
    float* rec = base + (size_t)c * RECF;
    float4 Gn = make_float4(0.f, 0.f, 0.f, 0.f);
    float gnn = 0.f, Mln = 0.f, Fn = 0.f;
    if (c + 1 < NC) {
      float* rn = rec + RECF;
      Gn = *(float4*)(rn + lane * 4);
      if (lane < 16) gnn = rn[256 + lane];
      Mln = rn[272]; Fn = rn[273];
    }
    // store the incoming state over the record
    *(float4*)(rec + lane * 4) = Sc;
    if (lane < 16) rec[256 + lane] = Sn;
    if (lane == 0) rec[272] = m;
    // state update (all stabilized exps <= 1)
    const float mx = fmaxf(m, Ml);
    const float al = __expf(m - mx);
    const float be = __expf(Ml - mx);
    Sc.x = fmaf(al, Sc.x, be * G.x);
    Sc.y = fmaf(al, Sc.y, be * G.y);
    Sc.z = fmaf(al, Sc.z, be * G.z);
    Sc.w = fmaf(al, Sc.w, be * G.w);
    Sn = fmaf(al, Sn, be * gn);
    m = F + mx;
    G = Gn; gn = gnn; Ml = Mln; F = Fn;
  }
}

// Pass 3: per-chunk sequential scan seeded from the stored chunk-start state.
// One wave per chunk; exact same per-step math as the monolithic scan.
__global__ void __launch_bounds__(64, 1)
chunk_scan_kernel(const unsigned short* __restrict__ q,
                  const unsigned short* __restrict__ k,
                  const unsigned short* __restrict__ v,
                  const float* __restrict__ itg,
                  const float* __restrict__ ftg,
                  const float* __restrict__ sum,
                  unsigned short* __restrict__ hout) {
  __shared__ float sk[CH * 16], sq[CH * 16], sv[CH * 16], sg[2 * CH];
  const int bid = blockIdx.x;
  const int bh  = bid >> 6;
  const int c   = bid & 63;
  const int b   = bh >> 6;
  const int h   = bh & 63;
  const int lane = threadIdx.x;
  const int e  = lane & 15;
  const int dg = lane >> 4;
  const int d0 = dg * 4;
  const size_t qkvb = ((size_t)bh * Lq + (size_t)c * CH) * 16;
  const size_t gb   = (size_t)bh * Lq + (size_t)c * CH;
  const size_t ob   = (size_t)b * Lq * Dq + (size_t)h * 16 + (size_t)c * CH * Dq;

  // load chunk-start state
  const float* rec = sum + (size_t)bid * RECF;
  const float4 Cv = *(const float4*)(rec + e * 16 + d0);
  const float4 nv = *(const float4*)(rec + 256 + d0);
  float m = rec[272];
  float C0 = Cv.x, C1 = Cv.y, C2 = Cv.z, C3 = Cv.w;
  float n0 = nv.x, n1 = nv.y, n2 = nv.z, n3 = nv.w;

  // stage the chunk tile
  const int xw = ((lane >> 1) & 3) << 2;
  {
    const unsigned short* kp = k + qkvb + (size_t)lane * 16;
    const unsigned short* qp = q + qkvb + (size_t)lane * 16;
    const unsigned short* vp = v + qkvb + (size_t)lane * 16;
    bf16x8 a0 = *(const bf16x8*)kp, a1 = *(const bf16x8*)(kp + 8);
    bf16x8 b0 = *(const bf16x8*)qp, b1 = *(const bf16x8*)(qp + 8);
    bf16x8 c0v = *(const bf16x8*)vp, c1v = *(const bf16x8*)(vp + 8);
    deposit16(sk + lane * 16, xw, a0, a1);
    deposit16(sq + lane * 16, xw, b0, b1);
    deposit16(sv + lane * 16, xw, c0v, c1v);
    sg[lane] = itg[gb + lane];
    sg[CH + lane] = ftg[gb + lane];
  }

#pragma unroll 4
  for (int s = 0; s < CH; ++s) {
    const int x = ((s >> 1) & 3) << 2;
    const float* kr = sk + s * 16;
    const float* qr = sq + s * 16;
    const float* vr = sv + s * 16;
    const float itc = sg[s];
    const float ftc = sg[CH + s];
    const float ke  = kr[e ^ x];
    const float4 kq4 = *(const float4*)(kr + (d0 ^ x));
    const float4 qq4 = *(const float4*)(qr + (d0 ^ x));
    const float4 vq4 = *(const float4*)(vr + (d0 ^ x));
    const float fm = ftc + m;
    const float mn = fmaxf(fm, itc);
    const float fg = __expf(fm - mn);   // <= 1
    const float ig = __expf(itc - mn);  // <= 1
    m = mn;
    const float a = ig * ke;
    C0 = fmaf(fg, C0, a * vq4.x);
    C1 = fmaf(fg, C1, a * vq4.y);
    C2 = fmaf(fg, C2, a * vq4.z);
    C3 = fmaf(fg, C3, a * vq4.w);
    n0 = fmaf(fg, n0, ig * kq4.x);
    n1 = fmaf(fg, n1, ig * kq4.y);
    n2 = fmaf(fg, n2, ig * kq4.z);
    n3 = fmaf(fg, n3, ig * kq4.w);
    float cq = fmaf(C3, qq4.w, fmaf(C2, qq4.z, fmaf(C1, qq4.y, C0 * qq4.x)));
    float dn = fmaf(n3, qq4.w, fmaf(n2, qq4.z, fmaf(n1, qq4.y, n0 * qq4.x)));
    cq += __shfl_xor(cq, 16, 64);
    cq += __shfl_xor(cq, 32, 64);
    dn += __shfl_xor(dn, 16, 64);
    dn += __shfl_xor(dn, 32, 64);
    const float denom = fmaxf(fabsf(dn), 1.0f);
    if (dg == 0) hout[ob + (size_t)s * Dq + e] = f2b(cq / denom);
  }
}

// ---------------- fallback: monolithic tiled scan (round-1, proven) ----------------
__global__ void __launch_bounds__(64, 1)
scan_kernel(const unsigned short* __restrict__ q,
            const unsigned short* __restrict__ k,
            const unsigned short* __restrict__ v,
            const float* __restrict__ itg,
            const float* __restrict__ ftg,
            unsigned short* __restrict__ hout) {
  __shared__ float sk[CH * 16], sq[CH * 16], sv[CH * 16], sg[2 * CH];
  const int bh = blockIdx.x;
  const int b  = bh >> 6;
  const int h  = bh & 63;
  const int lane = threadIdx.x;
  const int e  = lane & 15;
  const int dg = lane >> 4;
  const int d0 = dg * 4;
  const size_t qkvb = (size_t)bh * Lq * 16;
  const size_t gb   = (size_t)bh * Lq;
  const size_t ob   = (size_t)b * Lq * Dq + (size_t)h * 16;

  float C0 = 0, C1 = 0, C2 = 0, C3 = 0;
  float n0 = 0, n1 = 0, n2 = 0, n3 = 0;
  float m = 0.f;

  bf16x8 rk0, rk1, rq0, rq1, rv0, rv1;
  float rit, rft;
  {
    const unsigned short* kp = k + qkvb + (size_t)lane * 16;
    const unsigned short* qp = q + qkvb + (size_t)lane * 16;
    const unsigned short* vp = v + qkvb + (size_t)lane * 16;
    rk0 = *(const bf16x8*)kp; rk1 = *(const bf16x8*)(kp + 8);
    rq0 = *(const bf16x8*)qp; rq1 = *(const bf16x8*)(qp + 8);
    rv0 = *(const bf16x8*)vp; rv1 = *(const bf16x8*)(vp + 8);
    rit = itg[gb + lane]; rft = ftg[gb + lane];
  }

  const int xw = ((lane >> 1) & 3) << 2;
  const int NT = Lq / CH;
  for (int c = 0; c < NT; ++c) {
    deposit16(sk + lane * 16, xw, rk0, rk1);
    deposit16(sq + lane * 16, xw, rq0, rq1);
    deposit16(sv + lane * 16, xw, rv0, rv1);
    sg[lane] = rit; sg[CH + lane] = rft;
    if (c + 1 < NT) {
      const size_t off = qkvb + ((size_t)(c + 1) * CH + lane) * 16;
      const unsigned short* kp = k + off;
      const unsigned short* qp = q + off;
      const unsigned short* vp = v + off;
      rk0 = *(const bf16x8*)kp; rk1 = *(const bf16x8*)(kp + 8);
      rq0 = *(const bf16x8*)qp; rq1 = *(const bf16x8*)(qp + 8);
      rv0 = *(const bf16x8*)vp; rv1 = *(const bf16x8*)(vp + 8);
      rit = itg[gb + (size_t)(c + 1) * CH + lane];
      rft = ftg[gb + (size_t)(c + 1) * CH + lane];
    }
#pragma unroll 4
    for (int s = 0; s < CH; ++s) {
      const int x = ((s >> 1) & 3) << 2;
      const float* kr = sk + s * 16;
      const float* qr = sq + s * 16;
      const float* vr = sv + s * 16;
      const float itc = sg[s];
      const float ftc = sg[CH + s];
      const float ke  = kr[e ^ x];
      const float4 kq4 = *(const float4*)(kr + (d0 ^ x));
      const float4 qq4 = *(const float4*)(qr + (d0 ^ x));
      const float4 vq4 = *(const float4*)(vr + (d0 ^ x));
      const float fm = ftc + m;
      const float mn = fmaxf(fm, itc);
      const float fg = __expf(fm - mn);
      const float ig = __expf(itc - mn);
      m = mn;
      const float a = ig * ke;
      C0 = fmaf(fg, C0, a * vq4.x);
      C1 = fmaf(fg, C1, a * vq4.y);
      C2 = fmaf(fg, C2, a * vq4.z);
      C3 = fmaf(fg, C3, a * vq4.w);
      n0 = fmaf(fg, n0, ig * kq4.x);
      n1 = fmaf(fg, n1, ig * kq4.y);
      n2 = fmaf(fg, n2, ig * kq4.z);
      n3 = fmaf(fg, n3, ig * kq4.w);
      float cq = fmaf(C3, qq4.w, fmaf(C2, qq4.z, fmaf(C1, qq4.y, C0 * qq4.x)));
      float dn = fmaf(n3, qq4.w, fmaf(n2, qq4.z, fmaf(n1, qq4.y, n0 * qq4.x)));
      cq += __shfl_xor(cq, 16, 64);
      cq += __shfl_xor(cq, 32, 64);
      dn += __shfl_xor(dn, 16, 64);
      dn += __shfl_xor(dn, 32, 64);
      const float denom = fmaxf(fabsf(dn), 1.0f);
      if (dg == 0) hout[ob + (size_t)(c * CH + s) * Dq + e] = f2b(cq / denom);
    }
  }
}

extern "C" void kernel_launch(void* const* d_in, const int* in_sizes, int n_in,
                              void* d_out, int out_size, void* d_ws, size_t ws_size,
                              hipStream_t stream) {
  const void* x     = d_in[0];
  const void* gamma = d_in[1];
  const void* beta  = d_in[2];
  const void* qw    = d_in[3];
  const void* qbv   = d_in[4];
  const void* kw    = d_in[5];
  const void* kbv   = d_in[6];
  const void* vw    = d_in[7];
  const void* vbv   = d_in[8];
  const void* ow    = d_in[9];
  const void* obv   = d_in[10];
  const void* iw    = d_in[11];
  const void* ibv   = d_in[12];
  const void* fw    = d_in[13];
  const void* fbv   = d_in[14];

  const size_t bufBytes  = (size_t)Mq * Dq * 2;        // 64 MiB
  const size_t gateBytes = (size_t)Mq * Hq * 4;        // 8 MiB
  const size_t sumBytes  = (size_t)TC * RECF * 4;      // ~37.75 MiB
  const size_t need_old   = 4 * bufBytes + 2 * gateBytes + 4096;
  const size_t need_chunk = need_old + sumBytes;
  if (ws_size < need_old) {   // diagnostic: absmax ~= 1000 signals this branch
    sentinel_kernel<<<(out_size + 255) / 256, 256, 0, stream>>>((unsigned short*)d_out, out_size);
    return;
  }
  const int chunked = (ws_size >= need_chunk);

  char* ws = (char*)d_ws;
  unsigned short* xnb = (unsigned short*)ws; ws += bufBytes;   // reused as hbf
  unsigned short* qbf = (unsigned short*)ws; ws += bufBytes;
  unsigned short* kbf = (unsigned short*)ws; ws += bufBytes;
  unsigned short* vbf = (unsigned short*)ws; ws += bufBytes;
  float* itb = (float*)ws; ws += gateBytes;
  float* ftb = (float*)ws; ws += gateBytes;
  unsigned int* flagp = (unsigned int*)ws; ws += 4096;
  float* sumb = (float*)ws;
  unsigned short* hbf = xnb;  // alias: xn dead after the 5 projection GEMMs

  classify_kernel<<<1, 256, 0, stream>>>((const unsigned short*)qw, flagp);
  ln_kernel<<<Mq, 256, 0, stream>>>(x, gamma, beta, xnb, flagp);
  // q/k/v -> [B,H,L,16] bf16 (layout 1); gates -> [B,H,L] f32 (layout 2)
  gemm_bt<<<dim3(Mq / 128, 8), 256, 0, stream>>>(xnb, qw, qbv, nullptr, qbf, Dq, Dq, 1.0f,  0, 1, flagp);
  gemm_bt<<<dim3(Mq / 128, 8), 256, 0, stream>>>(xnb, kw, kbv, nullptr, kbf, Dq, Dq, 0.25f, 0, 1, flagp); // /sqrt(16)
  gemm_bt<<<dim3(Mq / 128, 8), 256, 0, stream>>>(xnb, vw, vbv, nullptr, vbf, Dq, Dq, 1.0f,  0, 1, flagp);
  gemm_bt<<<dim3(Mq / 128, 1), 256, 0, stream>>>(xnb, iw, ibv, nullptr, itb, Hq, Dq, 1.0f,  1, 2, flagp);
  gemm_bt<<<dim3(Mq / 128, 1), 256, 0, stream>>>(xnb, fw, fbv, nullptr, ftb, Hq, Dq, 1.0f,  1, 2, flagp);
  if (chunked) {
    summary_kernel<<<TC, 64, 0, stream>>>(kbf, vbf, itb, ftb, sumb);
    combine_kernel<<<Bq * Hq, 64, 0, stream>>>(sumb);
    chunk_scan_kernel<<<TC, 64, 0, stream>>>(qbf, kbf, vbf, itb, ftb, sumb, hbf);
  } else {
    scan_kernel<<<Bq * Hq, 64, 0, stream>>>(qbf, kbf, vbf, itb, ftb, hbf);
  }
  gemm_bt<<<dim3(Mq / 128, 8), 256, 0, stream>>>(hbf, ow, obv, x, d_out, Dq, Dq, 1.0f, 2, 0, flagp);
}

// Round 3
// 1214.751 us; speedup vs baseline: 2.4159x; 1.0370x over previous
//
#include <hip/hip_runtime.h>
#include <stdint.h>

// Problem dims (fixed)
#define Bq 8
#define Lq 4096
#define Dq 1024
#define Hq 64
#define Mq (Bq*Lq)   // 32768 rows
#define CH 64        // scan chunk length
#define NC (Lq/CH)   // 64 chunks per (b,h)
#define TC (Bq*Hq*NC) // 32768 chunk tasks
#define RECF 288     // f32 per chunk record: 256 C + 16 n + Ml + F + pad

typedef short bf16x8 __attribute__((ext_vector_type(8)));  // 8 bf16 in 4 VGPRs
typedef float f32x4  __attribute__((ext_vector_type(4)));

__device__ __forceinline__ float b2f(unsigned short u) {
  union { unsigned int i; float f; } v; v.i = ((unsigned int)u) << 16; return v.f;
}
__device__ __forceinline__ unsigned short f2b(float f) {
  union { float f; unsigned int i; } v; v.f = f;
  unsigned int r = v.i + 0x7fffu + ((v.i >> 16) & 1u);  // RNE
  return (unsigned short)(r >> 16);
}
__device__ __forceinline__ bf16x8 pack8(float4 a, float4 b) {
  bf16x8 r;
  r[0] = (short)f2b(a.x); r[1] = (short)f2b(a.y); r[2] = (short)f2b(a.z); r[3] = (short)f2b(a.w);
  r[4] = (short)f2b(b.x); r[5] = (short)f2b(b.y); r[6] = (short)f2b(b.z); r[7] = (short)f2b(b.w);
  return r;
}

// direct global->LDS DMA, 16 B per lane (dest = wave-uniform base + lane*16)
__device__ __forceinline__ void gload_lds16(const unsigned short* g, unsigned short* l) {
  __builtin_amdgcn_global_load_lds(
      (const __attribute__((address_space(1))) unsigned int*)g,
      (__attribute__((address_space(3))) unsigned int*)l, 16, 0, 0);
}

// ---------------- dtype classifier: is this buffer bf16 (1) or f32 (0)? ----------------
__global__ void classify_kernel(const unsigned short* __restrict__ w, unsigned int* flag) {
  __shared__ unsigned int s_nz, s_ib;
  if (threadIdx.x == 0) { s_nz = 0; s_ib = 0; }
  __syncthreads();
  unsigned int nz = 0, ib = 0;
  for (int i = threadIdx.x; i < 8192; i += 256) {
    unsigned short u = w[2 * i];
    if (u) {
      nz++;
      unsigned int e = (u >> 7) & 0xFFu;
      if (e >= 0x31u && e <= 0x9Du) ib++;
    }
  }
  atomicAdd(&s_nz, nz); atomicAdd(&s_ib, ib);
  __syncthreads();
  if (threadIdx.x == 0) *flag = (s_nz > 0 && 4u * s_ib >= 3u * s_nz) ? 1u : 0u;
}

// ---------------- ws-too-small sentinel ----------------
__global__ void sentinel_kernel(unsigned short* out, int n) {
  int i = blockIdx.x * 256 + threadIdx.x;
  if (i < n) out[i] = 0x447A;  // bf16 1000.0
}

// ---------------- weight convert: any dtype -> bf16 (same rounding as GEMM staging) ----
__global__ void wconv_kernel(const void* __restrict__ wv, unsigned short* __restrict__ o,
                             const unsigned int* __restrict__ flagp) {
  const int isbf = (int)*flagp;
  const size_t i = ((size_t)blockIdx.x * 256 + threadIdx.x) * 8;
  if (isbf) {
    *(bf16x8*)(o + i) = *(const bf16x8*)((const unsigned short*)wv + i);
  } else {
    const float* wf = (const float*)wv;
    float4 a = *(const float4*)(wf + i);
    float4 b = *(const float4*)(wf + i + 4);
    *(bf16x8*)(o + i) = pack8(a, b);
  }
}

// ---------------- LayerNorm: one block (256 thr) per row of 1024 ----------------
__global__ void ln_kernel(const void* __restrict__ xv,
                          const void* __restrict__ gv,
                          const void* __restrict__ bev,
                          unsigned short* __restrict__ xn,
                          const unsigned int* __restrict__ flagp) {
  const int isbf = (int)*flagp;
  const int row = blockIdx.x;
  const int t = threadIdx.x;
  const size_t base = (size_t)row * Dq;
  float v0, v1, v2, v3, g0, g1, g2, g3, e0, e1, e2, e3;
  if (isbf) {
    ushort4 u  = *(const ushort4*)((const unsigned short*)xv + base + t * 4);
    ushort4 g  = *(const ushort4*)((const unsigned short*)gv + t * 4);
    ushort4 be = *(const ushort4*)((const unsigned short*)bev + t * 4);
    v0 = b2f(u.x); v1 = b2f(u.y); v2 = b2f(u.z); v3 = b2f(u.w);
    g0 = b2f(g.x); g1 = b2f(g.y); g2 = b2f(g.z); g3 = b2f(g.w);
    e0 = b2f(be.x); e1 = b2f(be.y); e2 = b2f(be.z); e3 = b2f(be.w);
  } else {
    float4 u  = *(const float4*)((const float*)xv + base + t * 4);
    float4 g  = *(const float4*)((const float*)gv + t * 4);
    float4 be = *(const float4*)((const float*)bev + t * 4);
    v0 = u.x; v1 = u.y; v2 = u.z; v3 = u.w;
    g0 = g.x; g1 = g.y; g2 = g.z; g3 = g.w;
    e0 = be.x; e1 = be.y; e2 = be.z; e3 = be.w;
  }
  float s  = v0 + v1 + v2 + v3;
  float ss = v0*v0 + v1*v1 + v2*v2 + v3*v3;
#pragma unroll
  for (int off = 32; off >= 1; off >>= 1) {
    s  += __shfl_xor(s,  off, 64);
    ss += __shfl_xor(ss, off, 64);
  }
  __shared__ float sb[8];
  const int w = t >> 6, lane = t & 63;
  if (lane == 0) { sb[w] = s; sb[4 + w] = ss; }
  __syncthreads();
  s  = sb[0] + sb[1] + sb[2] + sb[3];
  ss = sb[4] + sb[5] + sb[6] + sb[7];
  const float mu   = s * (1.0f / Dq);
  const float var  = ss * (1.0f / Dq) - mu * mu;
  const float rstd = rsqrtf(var + 1e-5f);
  ushort4 o;
  o.x = f2b((v0 - mu) * rstd * g0 + e0);
  o.y = f2b((v1 - mu) * rstd * g1 + e1);
  o.z = f2b((v2 - mu) * rstd * g2 + e2);
  o.w = f2b((v3 - mu) * rstd * g3 + e3);
  *(ushort4*)(xn + base + t * 4) = o;
}

// ======== epilogue shared by both GEMMs (C/D layout col=lane&15, row=(lane>>4)*4+reg) ====
__device__ __forceinline__ void gemm_epilogue(
    f32x4 acc[4][4], int row0, int col0, int wm, int wn, int lane,
    const void* biasv, const void* residv, void* out,
    int N, float scale, int out_mode, int out_layout, int isbf) {
  const int colL = lane & 15;
  const int rq   = lane >> 4;
  const int wf32 = (out_mode == 1) || (out_mode == 2 && !isbf);
#pragma unroll
  for (int nt = 0; nt < 4; ++nt) {
    const int col = col0 + wn * 64 + nt * 16 + colL;
    if (col >= N) continue;
    const float bv = isbf ? b2f(((const unsigned short*)biasv)[col])
                          : ((const float*)biasv)[col];
#pragma unroll
    for (int mt = 0; mt < 4; ++mt) {
      const int rowb = row0 + wm * 64 + mt * 16 + rq * 4;
#pragma unroll
      for (int r = 0; r < 4; ++r) {
        const int row = rowb + r;
        size_t idx;
        if (out_layout == 1) {
          const int bb2 = row >> 12, t = row & 4095;           // L=4096
          idx = ((((size_t)bb2 * Hq + (col >> 4)) << 12) + t) * 16 + (col & 15);
        } else if (out_layout == 2) {
          const int bb2 = row >> 12, t = row & 4095;
          idx = (((size_t)bb2 * Hq + col) << 12) + t;
        } else {
          idx = (size_t)row * N + col;
        }
        float val = (acc[mt][nt][r] + bv) * scale;
        if (residv) {
          const size_t ridx = (size_t)row * N + col;           // resid always [M,N]
          val += isbf ? b2f(((const unsigned short*)residv)[ridx])
                      : ((const float*)residv)[ridx];
        }
        if (wf32) ((float*)out)[idx] = val;
        else ((unsigned short*)out)[idx] = f2b(val);
      }
    }
  }
}

// ---------------- MFMA GEMM (polymorphic W; reg-staged): gates + fallback path ----------
__global__ void gemm_bt(const unsigned short* __restrict__ A,
                        const void* __restrict__ Wv,
                        const void* __restrict__ biasv,
                        const void* __restrict__ residv,
                        void* __restrict__ out,
                        int N, int K, float scale, int out_mode, int out_layout,
                        const unsigned int* __restrict__ flagp) {
  __shared__ unsigned short smA[128 * 32];
  __shared__ unsigned short smB[128 * 32];
  const int isbf = (int)*flagp;
  const int tid  = threadIdx.x;
  const int w    = tid >> 6;
  const int lane = tid & 63;
  const int wm   = w >> 1;
  const int wn   = w & 1;
  const int row0 = blockIdx.x * 128;
  const int col0 = blockIdx.y * 128;

  const int c0 = tid, c1 = tid + 256;
  const int ar0 = row0 + (c0 >> 2), ak0 = (c0 & 3) * 8;
  const int ar1 = row0 + (c1 >> 2), ak1 = (c1 & 3) * 8;
  int br0 = col0 + (c0 >> 2), bk0 = (c0 & 3) * 8;
  int br1 = col0 + (c1 >> 2), bk1 = (c1 & 3) * 8;
  if (br0 >= N) br0 = N - 1;
  if (br1 >= N) br1 = N - 1;
  const size_t aro0 = (size_t)ar0 * K + ak0;
  const size_t aro1 = (size_t)ar1 * K + ak1;
  const size_t bro0 = (size_t)br0 * K + bk0;
  const size_t bro1 = (size_t)br1 * K + bk1;

  f32x4 acc[4][4];
#pragma unroll
  for (int i = 0; i < 4; ++i)
#pragma unroll
    for (int j = 0; j < 4; ++j) acc[i][j] = (f32x4){0.f, 0.f, 0.f, 0.f};

  const int mrow = lane & 15;
  const int kq8  = (lane >> 4) * 8;

  for (int k0 = 0; k0 < K; k0 += 32) {
    bf16x8 ta0 = *(const bf16x8*)(A + aro0 + k0);
    bf16x8 ta1 = *(const bf16x8*)(A + aro1 + k0);
    bf16x8 tb0, tb1;
    if (isbf) {
      const unsigned short* W = (const unsigned short*)Wv;
      tb0 = *(const bf16x8*)(W + bro0 + k0);
      tb1 = *(const bf16x8*)(W + bro1 + k0);
    } else {
      const float* W = (const float*)Wv;
      float4 w00 = *(const float4*)(W + bro0 + k0);
      float4 w01 = *(const float4*)(W + bro0 + k0 + 4);
      float4 w10 = *(const float4*)(W + bro1 + k0);
      float4 w11 = *(const float4*)(W + bro1 + k0 + 4);
      tb0 = pack8(w00, w01);
      tb1 = pack8(w10, w11);
    }
    __syncthreads();
    *(bf16x8*)(smA + c0 * 8) = ta0;
    *(bf16x8*)(smA + c1 * 8) = ta1;
    *(bf16x8*)(smB + c0 * 8) = tb0;
    *(bf16x8*)(smB + c1 * 8) = tb1;
    __syncthreads();
    bf16x8 a[4], bb[4];
#pragma unroll
    for (int mt = 0; mt < 4; ++mt)
      a[mt] = *(const bf16x8*)(smA + (wm * 64 + mt * 16 + mrow) * 32 + kq8);
#pragma unroll
    for (int nt = 0; nt < 4; ++nt)
      bb[nt] = *(const bf16x8*)(smB + (wn * 64 + nt * 16 + mrow) * 32 + kq8);
#pragma unroll
    for (int mt = 0; mt < 4; ++mt)
#pragma unroll
      for (int nt = 0; nt < 4; ++nt)
        acc[mt][nt] = __builtin_amdgcn_mfma_f32_16x16x32_bf16(a[mt], bb[nt], acc[mt][nt], 0, 0, 0);
  }
  gemm_epilogue(acc, row0, col0, wm, wn, lane, biasv, residv, out,
                N, scale, out_mode, out_layout, isbf);
}

// ---------------- fast MFMA GEMM: bf16 A and W, global_load_lds staging (m97) ----------
// N == K == Dq fixed. W must be pre-converted bf16 [N][K].
__global__ void __launch_bounds__(256)
gemm16(const unsigned short* __restrict__ A,
       const unsigned short* __restrict__ W,
       const void* __restrict__ biasv,
       const void* __restrict__ residv,
       void* __restrict__ out,
       float scale, int out_mode, int out_layout,
       const unsigned int* __restrict__ flagp) {
  __shared__ unsigned short smA[128 * 32];
  __shared__ unsigned short smB[128 * 32];
  const int isbf = (int)*flagp;
  const int tid  = threadIdx.x;
  const int w    = tid >> 6;
  const int lane = tid & 63;
  const int wm   = w >> 1;
  const int wn   = w & 1;
  const int row0 = blockIdx.x * 128;
  const int col0 = blockIdx.y * 128;

  // staging: wave w stages chunks {2w, 2w+1}; chunk c = 16 rows; lane covers
  // row = c*16 + (lane>>2), k8 = (lane&3)*8.  LDS dest wave-uniform: chunk base.
  const int rA0 = (w * 2) * 16 + (lane >> 2);
  const size_t aoff0 = (size_t)(row0 + rA0) * Dq + (lane & 3) * 8;
  const size_t aoff1 = aoff0 + (size_t)16 * Dq;
  const size_t boff0 = (size_t)(col0 + rA0) * Dq + (lane & 3) * 8;
  const size_t boff1 = boff0 + (size_t)16 * Dq;
  unsigned short* ldsA0 = smA + w * 1024;        // chunk 2w   (512 ushorts = 1 KiB)
  unsigned short* ldsA1 = smA + w * 1024 + 512;  // chunk 2w+1
  unsigned short* ldsB0 = smB + w * 1024;
  unsigned short* ldsB1 = smB + w * 1024 + 512;

  f32x4 acc[4][4];
#pragma unroll
  for (int i = 0; i < 4; ++i)
#pragma unroll
    for (int j = 0; j < 4; ++j) acc[i][j] = (f32x4){0.f, 0.f, 0.f, 0.f};

  const int mrow = lane & 15;
  const int kq8  = (lane >> 4) * 8;

  for (int k0 = 0; k0 < Dq; k0 += 32) {
    __syncthreads();   // prev iteration's ds_reads done before overwrite
    gload_lds16(A + aoff0 + k0, ldsA0);
    gload_lds16(A + aoff1 + k0, ldsA1);
    gload_lds16(W + boff0 + k0, ldsB0);
    gload_lds16(W + boff1 + k0, ldsB1);
    __syncthreads();   // compiler drains vmcnt(0) before barrier -> tiles ready
    bf16x8 a[4], bb[4];
#pragma unroll
    for (int mt = 0; mt < 4; ++mt)
      a[mt] = *(const bf16x8*)(smA + (wm * 64 + mt * 16 + mrow) * 32 + kq8);
#pragma unroll
    for (int nt = 0; nt < 4; ++nt)
      bb[nt] = *(const bf16x8*)(smB + (wn * 64 + nt * 16 + mrow) * 32 + kq8);
#pragma unroll
    for (int mt = 0; mt < 4; ++mt)
#pragma unroll
      for (int nt = 0; nt < 4; ++nt)
        acc[mt][nt] = __builtin_amdgcn_mfma_f32_16x16x32_bf16(a[mt], bb[nt], acc[mt][nt], 0, 0, 0);
  }
  gemm_epilogue(acc, row0, col0, wm, wn, lane, biasv, residv, out,
                Dq, scale, out_mode, out_layout, isbf);
}

// ---------------- shared helper: bf16x16 row -> f32 LDS row with quad swizzle ----------
__device__ __forceinline__ void deposit16(float* __restrict__ dstrow, int xw,
                                          bf16x8 lo, bf16x8 hi) {
  float t[16];
#pragma unroll
  for (int j = 0; j < 8; ++j) t[j] = b2f((unsigned short)lo[j]);
#pragma unroll
  for (int j = 0; j < 8; ++j) t[8 + j] = b2f((unsigned short)hi[j]);
#pragma unroll
  for (int qd = 0; qd < 4; ++qd) {
    *(float4*)(dstrow + ((qd << 2) ^ xw)) =
        make_float4(t[qd * 4], t[qd * 4 + 1], t[qd * 4 + 2], t[qd * 4 + 3]);
  }
}

// =================== chunked-parallel mLSTM scan ===================
// Decomposition: F_t = prefix-sum(f), w_s = i_s - F_s, m_t = F_t + max(m_in, max_{s<=t} w_s)
//   C_t = exp(m_in + F_t - m_t) C_in + exp(F_t - m_t) sum_{s<=t} exp(w_s) v_s k_s^T
// Record layout (f32, per chunk, stride RECF): [e*16+d] C_{d,e}; [256+d] n_d; [272] Ml/m_in; [273] F.

// Pass 1: per-chunk summaries (fully parallel, one wave per chunk)
__global__ void __launch_bounds__(64, 1)
summary_kernel(const unsigned short* __restrict__ k,
               const unsigned short* __restrict__ v,
               const float* __restrict__ itg,
               const float* __restrict__ ftg,
               float* __restrict__ sum) {
  __shared__ float sk[CH * 16], sv[CH * 16], sp[CH];
  const int bid = blockIdx.x;
  const int bh  = bid >> 6;            // NC == 64
  const int c   = bid & 63;
  const int lane = threadIdx.x;
  const int e  = lane & 15;
  const int dg = lane >> 4;
  const int d0 = dg * 4;
  const size_t qkvb = ((size_t)bh * Lq + (size_t)c * CH) * 16;
  const size_t gb   = (size_t)bh * Lq + (size_t)c * CH;

  // per-lane gates; lane index == local timestep
  float fv = ftg[gb + lane];
  float iv = itg[gb + lane];
  // inclusive prefix-sum of f across the wave
  float F = fv;
#pragma unroll
  for (int off = 1; off < 64; off <<= 1) {
    float tt = __shfl_up(F, off, 64);
    if (lane >= off) F += tt;
  }
  float wv = iv - F;
  float Ml = wv;
#pragma unroll
  for (int off = 1; off < 64; off <<= 1)
    Ml = fmaxf(Ml, __shfl_xor(Ml, off, 64));
  const float Ftot = __shfl(F, 63, 64);

  const int xw = ((lane >> 1) & 3) << 2;
  {
    const unsigned short* kp = k + qkvb + (size_t)lane * 16;
    const unsigned short* vp = v + qkvb + (size_t)lane * 16;
    bf16x8 a0 = *(const bf16x8*)kp, a1 = *(const bf16x8*)(kp + 8);
    bf16x8 b0 = *(const bf16x8*)vp, b1 = *(const bf16x8*)(vp + 8);
    deposit16(sk + lane * 16, xw, a0, a1);
    deposit16(sv + lane * 16, xw, b0, b1);
    sp[lane] = __expf(wv - Ml);   // p_s in (0,1]
  }
  float C0 = 0, C1 = 0, C2 = 0, C3 = 0;
  float g0 = 0, g1 = 0, g2 = 0, g3 = 0;
#pragma unroll 4
  for (int s = 0; s < CH; ++s) {
    const int x = ((s >> 1) & 3) << 2;
    const float* kr = sk + s * 16;
    const float* vr = sv + s * 16;
    const float p  = sp[s];
    const float ke = kr[e ^ x];
    const float4 kq = *(const float4*)(kr + (d0 ^ x));
    const float4 vq = *(const float4*)(vr + (d0 ^ x));
    const float a = p * ke;
    C0 = fmaf(a, vq.x, C0); C1 = fmaf(a, vq.y, C1);
    C2 = fmaf(a, vq.z, C2); C3 = fmaf(a, vq.w, C3);
    g0 = fmaf(p, kq.x, g0); g1 = fmaf(p, kq.y, g1);
    g2 = fmaf(p, kq.z, g2); g3 = fmaf(p, kq.w, g3);
  }
  float* rec = sum + (size_t)bid * RECF;
  *(float4*)(rec + e * 16 + d0) = make_float4(C0, C1, C2, C3);
  if (e == 0) *(float4*)(rec + 256 + d0) = make_float4(g0, g1, g2, g3);
  if (lane == 0) { rec[272] = Ml; rec[273] = Ftot; }
}

// Pass 2: sequential combine over chunks per (b,h); rewrites each record with the
// INCOMING (chunk-start) state in place.
__global__ void __launch_bounds__(64, 1)
combine_kernel(float* __restrict__ sum) {
  const int bh = blockIdx.x;
  const int lane = threadIdx.x;
  float* base = sum + (size_t)bh * NC * RECF;
  float4 Sc = make_float4(0.f, 0.f, 0.f, 0.f);
  float Sn = 0.f;
  float m = 0.f;
  // prefetch chunk 0
  float4 G = *(float4*)(base + lane * 4);
  float gn = (lane < 16) ? base[256 + lane] : 0.f;
  float Ml = base[272], F = base[273];
  for (int c = 0; c < NC; ++c) {
    float* rec = base + (size_t)c * RECF;
    float4 Gn = make_float4(0.f, 0.f, 0.f, 0.f);
    float gnn = 0.f, Mln = 0.f, Fn = 0.f;
    if (c + 1 < NC) {
      float* rn = rec + RECF;
      Gn = *(float4*)(rn + lane * 4);
      if (lane < 16) gnn = rn[256 + lane];
      Mln = rn[272]; Fn = rn[273];
    }
    // store the incoming state over the record
    *(float4*)(rec + lane * 4) = Sc;
    if (lane < 16) rec[256 + lane] = Sn;
    if (lane == 0) rec[272] = m;
    // state update (all stabilized exps <= 1)
    const float mx = fmaxf(m, Ml);
    const float al = __expf(m - mx);
    const float be = __expf(Ml - mx);
    Sc.x = fmaf(al, Sc.x, be * G.x);
    Sc.y = fmaf(al, Sc.y, be * G.y);
    Sc.z = fmaf(al, Sc.z, be * G.z);
    Sc.w = fmaf(al, Sc.w, be * G.w);
    Sn = fmaf(al, Sn, be * gn);
    m = F + mx;
    G = Gn; gn = gnn; Ml = Mln; F = Fn;
  }
}

// Pass 3: per-chunk sequential scan seeded from the stored chunk-start state.
__global__ void __launch_bounds__(64, 1)
chunk_scan_kernel(const unsigned short* __restrict__ q,
                  const unsigned short* __restrict__ k,
                  const unsigned short* __restrict__ v,
                  const float* __restrict__ itg,
                  const float* __restrict__ ftg,
                  const float* __restrict__ sum,
                  unsigned short* __restrict__ hout) {
  __shared__ float sk[CH * 16], sq[CH * 16], sv[CH * 16], sg[2 * CH];
  const int bid = blockIdx.x;
  const int bh  = bid >> 6;
  const int c   = bid & 63;
  const int b   = bh >> 6;
  const int h   = bh & 63;
  const int lane = threadIdx.x;
  const int e  = lane & 15;
  const int dg = lane >> 4;
  const int d0 = dg * 4;
  const size_t qkvb = ((size_t)bh * Lq + (size_t)c * CH) * 16;
  const size_t gb   = (size_t)bh * Lq + (size_t)c * CH;
  const size_t ob   = (size_t)b * Lq * Dq + (size_t)h * 16 + (size_t)c * CH * Dq;

  // load chunk-start state
  const float* rec = sum + (size_t)bid * RECF;
  const float4 Cv = *(const float4*)(rec + e * 16 + d0);
  const float4 nv = *(const float4*)(rec + 256 + d0);
  float m = rec[272];
  float C0 = Cv.x, C1 = Cv.y, C2 = Cv.z, C3 = Cv.w;
  float n0 = nv.x, n1 = nv.y, n2 = nv.z, n3 = nv.w;

  // stage the chunk tile
  const int xw = ((lane >> 1) & 3) << 2;
  {
    const unsigned short* kp = k + qkvb + (size_t)lane * 16;
    const unsigned short* qp = q + qkvb + (size_t)lane * 16;
    const unsigned short* vp = v + qkvb + (size_t)lane * 16;
    bf16x8 a0 = *(const bf16x8*)kp, a1 = *(const bf16x8*)(kp + 8);
    bf16x8 b0 = *(const bf16x8*)qp, b1 = *(const bf16x8*)(qp + 8);
    bf16x8 c0v = *(const bf16x8*)vp, c1v = *(const bf16x8*)(vp + 8);
    deposit16(sk + lane * 16, xw, a0, a1);
    deposit16(sq + lane * 16, xw, b0, b1);
    deposit16(sv + lane * 16, xw, c0v, c1v);
    sg[lane] = itg[gb + lane];
    sg[CH + lane] = ftg[gb + lane];
  }

#pragma unroll 4
  for (int s = 0; s < CH; ++s) {
    const int x = ((s >> 1) & 3) << 2;
    const float* kr = sk + s * 16;
    const float* qr = sq + s * 16;
    const float* vr = sv + s * 16;
    const float itc = sg[s];
    const float ftc = sg[CH + s];
    const float ke  = kr[e ^ x];
    const float4 kq4 = *(const float4*)(kr + (d0 ^ x));
    const float4 qq4 = *(const float4*)(qr + (d0 ^ x));
    const float4 vq4 = *(const float4*)(vr + (d0 ^ x));
    const float fm = ftc + m;
    const float mn = fmaxf(fm, itc);
    const float fg = __expf(fm - mn);   // <= 1
    const float ig = __expf(itc - mn);  // <= 1
    m = mn;
    const float a = ig * ke;
    C0 = fmaf(fg, C0, a * vq4.x);
    C1 = fmaf(fg, C1, a * vq4.y);
    C2 = fmaf(fg, C2, a * vq4.z);
    C3 = fmaf(fg, C3, a * vq4.w);
    n0 = fmaf(fg, n0, ig * kq4.x);
    n1 = fmaf(fg, n1, ig * kq4.y);
    n2 = fmaf(fg, n2, ig * kq4.z);
    n3 = fmaf(fg, n3, ig * kq4.w);
    float cq = fmaf(C3, qq4.w, fmaf(C2, qq4.z, fmaf(C1, qq4.y, C0 * qq4.x)));
    float dn = fmaf(n3, qq4.w, fmaf(n2, qq4.z, fmaf(n1, qq4.y, n0 * qq4.x)));
    cq += __shfl_xor(cq, 16, 64);
    cq += __shfl_xor(cq, 32, 64);
    dn += __shfl_xor(dn, 16, 64);
    dn += __shfl_xor(dn, 32, 64);
    const float denom = fmaxf(fabsf(dn), 1.0f);
    if (dg == 0) hout[ob + (size_t)s * Dq + e] = f2b(cq / denom);
  }
}

// ---------------- fallback: monolithic tiled scan (round-1, proven) ----------------
__global__ void __launch_bounds__(64, 1)
scan_kernel(const unsigned short* __restrict__ q,
            const unsigned short* __restrict__ k,
            const unsigned short* __restrict__ v,
            const float* __restrict__ itg,
            const float* __restrict__ ftg,
            unsigned short* __restrict__ hout) {
  __shared__ float sk[CH * 16], sq[CH * 16], sv[CH * 16], sg[2 * CH];
  const int bh = blockIdx.x;
  const int b  = bh >> 6;
  const int h  = bh & 63;
  const int lane = threadIdx.x;
  const int e  = lane & 15;
  const int dg = lane >> 4;
  const int d0 = dg * 4;
  const size_t qkvb = (size_t)bh * Lq * 16;
  const size_t gb   = (size_t)bh * Lq;
  const size_t ob   = (size_t)b * Lq * Dq + (size_t)h * 16;

  float C0 = 0, C1 = 0, C2 = 0, C3 = 0;
  float n0 = 0, n1 = 0, n2 = 0, n3 = 0;
  float m = 0.f;

  bf16x8 rk0, rk1, rq0, rq1, rv0, rv1;
  float rit, rft;
  {
    const unsigned short* kp = k + qkvb + (size_t)lane * 16;
    const unsigned short* qp = q + qkvb + (size_t)lane * 16;
    const unsigned short* vp = v + qkvb + (size_t)lane * 16;
    rk0 = *(const bf16x8*)kp; rk1 = *(const bf16x8*)(kp + 8);
    rq0 = *(const bf16x8*)qp; rq1 = *(const bf16x8*)(qp + 8);
    rv0 = *(const bf16x8*)vp; rv1 = *(const bf16x8*)(vp + 8);
    rit = itg[gb + lane]; rft = ftg[gb + lane];
  }

  const int xw = ((lane >> 1) & 3) << 2;
  const int NT = Lq / CH;
  for (int c = 0; c < NT; ++c) {
    deposit16(sk + lane * 16, xw, rk0, rk1);
    deposit16(sq + lane * 16, xw, rq0, rq1);
    deposit16(sv + lane * 16, xw, rv0, rv1);
    sg[lane] = rit; sg[CH + lane] = rft;
    if (c + 1 < NT) {
      const size_t off = qkvb + ((size_t)(c + 1) * CH + lane) * 16;
      const unsigned short* kp = k + off;
      const unsigned short* qp = q + off;
      const unsigned short* vp = v + off;
      rk0 = *(const bf16x8*)kp; rk1 = *(const bf16x8*)(kp + 8);
      rq0 = *(const bf16x8*)qp; rq1 = *(const bf16x8*)(qp + 8);
      rv0 = *(const bf16x8*)vp; rv1 = *(const bf16x8*)(vp + 8);
      rit = itg[gb + (size_t)(c + 1) * CH + lane];
      rft = ftg[gb + (size_t)(c + 1) * CH + lane];
    }
#pragma unroll 4
    for (int s = 0; s < CH; ++s) {
      const int x = ((s >> 1) & 3) << 2;
      const float* kr = sk + s * 16;
      const float* qr = sq + s * 16;
      const float* vr = sv + s * 16;
      const float itc = sg[s];
      const float ftc = sg[CH + s];
      const float ke  = kr[e ^ x];
      const float4 kq4 = *(const float4*)(kr + (d0 ^ x));
      const float4 qq4 = *(const float4*)(qr + (d0 ^ x));
      const float4 vq4 = *(const float4*)(vr + (d0 ^ x));
      const float fm = ftc + m;
      const float mn = fmaxf(fm, itc);
      const float fg = __expf(fm - mn);
      const float ig = __expf(itc - mn);
      m = mn;
      const float a = ig * ke;
      C0 = fmaf(fg, C0, a * vq4.x);
      C1 = fmaf(fg, C1, a * vq4.y);
      C2 = fmaf(fg, C2, a * vq4.z);
      C3 = fmaf(fg, C3, a * vq4.w);
      n0 = fmaf(fg, n0, ig * kq4.x);
      n1 = fmaf(fg, n1, ig * kq4.y);
      n2 = fmaf(fg, n2, ig * kq4.z);
      n3 = fmaf(fg, n3, ig * kq4.w);
      float cq = fmaf(C3, qq4.w, fmaf(C2, qq4.z, fmaf(C1, qq4.y, C0 * qq4.x)));
      float dn = fmaf(n3, qq4.w, fmaf(n2, qq4.z, fmaf(n1, qq4.y, n0 * qq4.x)));
      cq += __shfl_xor(cq, 16, 64);
      cq += __shfl_xor(cq, 32, 64);
      dn += __shfl_xor(dn, 16, 64);
      dn += __shfl_xor(dn, 32, 64);
      const float denom = fmaxf(fabsf(dn), 1.0f);
      if (dg == 0) hout[ob + (size_t)(c * CH + s) * Dq + e] = f2b(cq / denom);
    }
  }
}

extern "C" void kernel_launch(void* const* d_in, const int* in_sizes, int n_in,
                              void* d_out, int out_size, void* d_ws, size_t ws_size,
                              hipStream_t stream) {
  const void* x     = d_in[0];
  const void* gamma = d_in[1];
  const void* beta  = d_in[2];
  const void* qw    = d_in[3];
  const void* qbv   = d_in[4];
  const void* kw    = d_in[5];
  const void* kbv   = d_in[6];
  const void* vw    = d_in[7];
  const void* vbv   = d_in[8];
  const void* ow    = d_in[9];
  const void* obv   = d_in[10];
  const void* iw    = d_in[11];
  const void* ibv   = d_in[12];
  const void* fw    = d_in[13];
  const void* fbv   = d_in[14];

  const size_t bufBytes  = (size_t)Mq * Dq * 2;        // 64 MiB
  const size_t gateBytes = (size_t)Mq * Hq * 4;        // 8 MiB
  const size_t sumBytes  = (size_t)TC * RECF * 4;      // ~37.75 MiB
  const size_t wBytes    = (size_t)Dq * Dq * 2;        // 2 MiB per converted weight
  const size_t need_old   = 4 * bufBytes + 2 * gateBytes + 4096;
  const size_t need_chunk = need_old + sumBytes;
  const size_t need_fast  = need_chunk + 4 * wBytes;
  if (ws_size < need_old) {   // diagnostic: absmax ~= 1000 signals this branch
    sentinel_kernel<<<(out_size + 255) / 256, 256, 0, stream>>>((unsigned short*)d_out, out_size);
    return;
  }
  const int chunked = (ws_size >= need_chunk);
  const int fast    = (ws_size >= need_fast);

  char* ws = (char*)d_ws;
  unsigned short* xnb = (unsigned short*)ws; ws += bufBytes;   // reused as hbf
  unsigned short* qbf = (unsigned short*)ws; ws += bufBytes;
  unsigned short* kbf = (unsigned short*)ws; ws += bufBytes;
  unsigned short* vbf = (unsigned short*)ws; ws += bufBytes;
  float* itb = (float*)ws; ws += gateBytes;
  float* ftb = (float*)ws; ws += gateBytes;
  unsigned int* flagp = (unsigned int*)ws; ws += 4096;
  float* sumb = (float*)ws; ws += sumBytes;
  unsigned short* wqb = (unsigned short*)ws; ws += wBytes;
  unsigned short* wkb = (unsigned short*)ws; ws += wBytes;
  unsigned short* wvb = (unsigned short*)ws; ws += wBytes;
  unsigned short* wob = (unsigned short*)ws; ws += wBytes;
  unsigned short* hbf = xnb;  // alias: xn dead after the 5 projection GEMMs

  classify_kernel<<<1, 256, 0, stream>>>((const unsigned short*)qw, flagp);
  ln_kernel<<<Mq, 256, 0, stream>>>(x, gamma, beta, xnb, flagp);
  // q/k/v -> [B,H,L,16] bf16 (layout 1); gates -> [B,H,L] f32 (layout 2)
  if (fast) {
    const int wgrid = (Dq * Dq / 8) / 256;   // 512 blocks
    wconv_kernel<<<wgrid, 256, 0, stream>>>(qw, wqb, flagp);
    wconv_kernel<<<wgrid, 256, 0, stream>>>(kw, wkb, flagp);
    wconv_kernel<<<wgrid, 256, 0, stream>>>(vw, wvb, flagp);
    wconv_kernel<<<wgrid, 256, 0, stream>>>(ow, wob, flagp);
    gemm16<<<dim3(Mq / 128, Dq / 128), 256, 0, stream>>>(xnb, wqb, qbv, nullptr, qbf, 1.0f,  0, 1, flagp);
    gemm16<<<dim3(Mq / 128, Dq / 128), 256, 0, stream>>>(xnb, wkb, kbv, nullptr, kbf, 0.25f, 0, 1, flagp); // /sqrt(16)
    gemm16<<<dim3(Mq / 128, Dq / 128), 256, 0, stream>>>(xnb, wvb, vbv, nullptr, vbf, 1.0f,  0, 1, flagp);
  } else {
    gemm_bt<<<dim3(Mq / 128, 8), 256, 0, stream>>>(xnb, qw, qbv, nullptr, qbf, Dq, Dq, 1.0f,  0, 1, flagp);
    gemm_bt<<<dim3(Mq / 128, 8), 256, 0, stream>>>(xnb, kw, kbv, nullptr, kbf, Dq, Dq, 0.25f, 0, 1, flagp);
    gemm_bt<<<dim3(Mq / 128, 8), 256, 0, stream>>>(xnb, vw, vbv, nullptr, vbf, Dq, Dq, 1.0f,  0, 1, flagp);
  }
  gemm_bt<<<dim3(Mq / 128, 1), 256, 0, stream>>>(xnb, iw, ibv, nullptr, itb, Hq, Dq, 1.0f,  1, 2, flagp);
  gemm_bt<<<dim3(Mq / 128, 1), 256, 0, stream>>>(xnb, fw, fbv, nullptr, ftb, Hq, Dq, 1.0f,  1, 2, flagp);
  if (chunked) {
    summary_kernel<<<TC, 64, 0, stream>>>(kbf, vbf, itb, ftb, sumb);
    combine_kernel<<<Bq * Hq, 64, 0, stream>>>(sumb);
    chunk_scan_kernel<<<TC, 64, 0, stream>>>(qbf, kbf, vbf, itb, ftb, sumb, hbf);
  } else {
    scan_kernel<<<Bq * Hq, 64, 0, stream>>>(qbf, kbf, vbf, itb, ftb, hbf);
  }
  if (fast) {
    gemm16<<<dim3(Mq / 128, Dq / 128), 256, 0, stream>>>(hbf, wob, obv, x, d_out, 1.0f, 2, 0, flagp);
  } else {
    gemm_bt<<<dim3(Mq / 128, 8), 256, 0, stream>>>(hbf, ow, obv, x, d_out, Dq, Dq, 1.0f, 2, 0, flagp);
  }
}

// Round 4
// 1160.729 us; speedup vs baseline: 2.5284x; 1.0465x over previous
//
#include <hip/hip_runtime.h>
#include <stdint.h>

// Problem dims (fixed)
#define Bq 8
#define Lq 4096
#define Dq 1024
#define Hq 64
#define Mq (Bq*Lq)   // 32768 rows
#define CH 64        // scan chunk length
#define NC (Lq/CH)   // 64 chunks per (b,h)
#define TC (Bq*Hq*NC) // 32768 chunk tasks
#define RECF 288     // f32 per chunk record: 256 C + 16 n + Ml + F + pad

typedef short bf16x8 __attribute__((ext_vector_type(8)));  // 8 bf16 in 4 VGPRs
typedef float f32x4  __attribute__((ext_vector_type(4)));

__device__ __forceinline__ float b2f(unsigned short u) {
  union { unsigned int i; float f; } v; v.i = ((unsigned int)u) << 16; return v.f;
}
__device__ __forceinline__ unsigned short f2b(float f) {
  union { float f; unsigned int i; } v; v.f = f;
  unsigned int r = v.i + 0x7fffu + ((v.i >> 16) & 1u);  // RNE
  return (unsigned short)(r >> 16);
}
__device__ __forceinline__ bf16x8 pack8(float4 a, float4 b) {
  bf16x8 r;
  r[0] = (short)f2b(a.x); r[1] = (short)f2b(a.y); r[2] = (short)f2b(a.z); r[3] = (short)f2b(a.w);
  r[4] = (short)f2b(b.x); r[5] = (short)f2b(b.y); r[6] = (short)f2b(b.z); r[7] = (short)f2b(b.w);
  return r;
}

// direct global->LDS DMA, 16 B per lane (dest = wave-uniform base + lane*16)
__device__ __forceinline__ void gload_lds16(const unsigned short* g, unsigned short* l) {
  __builtin_amdgcn_global_load_lds(
      (const __attribute__((address_space(1))) unsigned int*)g,
      (__attribute__((address_space(3))) unsigned int*)l, 16, 0, 0);
}

// ---------------- dtype classifier: is this buffer bf16 (1) or f32 (0)? ----------------
__global__ void classify_kernel(const unsigned short* __restrict__ w, unsigned int* flag) {
  __shared__ unsigned int s_nz, s_ib;
  if (threadIdx.x == 0) { s_nz = 0; s_ib = 0; }
  __syncthreads();
  unsigned int nz = 0, ib = 0;
  for (int i = threadIdx.x; i < 8192; i += 256) {
    unsigned short u = w[2 * i];
    if (u) {
      nz++;
      unsigned int e = (u >> 7) & 0xFFu;
      if (e >= 0x31u && e <= 0x9Du) ib++;
    }
  }
  atomicAdd(&s_nz, nz); atomicAdd(&s_ib, ib);
  __syncthreads();
  if (threadIdx.x == 0) *flag = (s_nz > 0 && 4u * s_ib >= 3u * s_nz) ? 1u : 0u;
}

// ---------------- ws-too-small sentinel ----------------
__global__ void sentinel_kernel(unsigned short* out, int n) {
  int i = blockIdx.x * 256 + threadIdx.x;
  if (i < n) out[i] = 0x447A;  // bf16 1000.0
}

// ---------------- weight convert: any dtype -> bf16 (same rounding as GEMM staging) ----
__global__ void wconv_kernel(const void* __restrict__ wv, unsigned short* __restrict__ o,
                             const unsigned int* __restrict__ flagp) {
  const int isbf = (int)*flagp;
  const size_t i = ((size_t)blockIdx.x * 256 + threadIdx.x) * 8;
  if (isbf) {
    *(bf16x8*)(o + i) = *(const bf16x8*)((const unsigned short*)wv + i);
  } else {
    const float* wf = (const float*)wv;
    float4 a = *(const float4*)(wf + i);
    float4 b = *(const float4*)(wf + i + 4);
    *(bf16x8*)(o + i) = pack8(a, b);
  }
}

// ---------------- LayerNorm: one block (256 thr) per row of 1024 ----------------
__global__ void ln_kernel(const void* __restrict__ xv,
                          const void* __restrict__ gv,
                          const void* __restrict__ bev,
                          unsigned short* __restrict__ xn,
                          const unsigned int* __restrict__ flagp) {
  const int isbf = (int)*flagp;
  const int row = blockIdx.x;
  const int t = threadIdx.x;
  const size_t base = (size_t)row * Dq;
  float v0, v1, v2, v3, g0, g1, g2, g3, e0, e1, e2, e3;
  if (isbf) {
    ushort4 u  = *(const ushort4*)((const unsigned short*)xv + base + t * 4);
    ushort4 g  = *(const ushort4*)((const unsigned short*)gv + t * 4);
    ushort4 be = *(const ushort4*)((const unsigned short*)bev + t * 4);
    v0 = b2f(u.x); v1 = b2f(u.y); v2 = b2f(u.z); v3 = b2f(u.w);
    g0 = b2f(g.x); g1 = b2f(g.y); g2 = b2f(g.z); g3 = b2f(g.w);
    e0 = b2f(be.x); e1 = b2f(be.y); e2 = b2f(be.z); e3 = b2f(be.w);
  } else {
    float4 u  = *(const float4*)((const float*)xv + base + t * 4);
    float4 g  = *(const float4*)((const float*)gv + t * 4);
    float4 be = *(const float4*)((const float*)bev + t * 4);
    v0 = u.x; v1 = u.y; v2 = u.z; v3 = u.w;
    g0 = g.x; g1 = g.y; g2 = g.z; g3 = g.w;
    e0 = be.x; e1 = be.y; e2 = be.z; e3 = be.w;
  }
  float s  = v0 + v1 + v2 + v3;
  float ss = v0*v0 + v1*v1 + v2*v2 + v3*v3;
#pragma unroll
  for (int off = 32; off >= 1; off >>= 1) {
    s  += __shfl_xor(s,  off, 64);
    ss += __shfl_xor(ss, off, 64);
  }
  __shared__ float sb[8];
  const int w = t >> 6, lane = t & 63;
  if (lane == 0) { sb[w] = s; sb[4 + w] = ss; }
  __syncthreads();
  s  = sb[0] + sb[1] + sb[2] + sb[3];
  ss = sb[4] + sb[5] + sb[6] + sb[7];
  const float mu   = s * (1.0f / Dq);
  const float var  = ss * (1.0f / Dq) - mu * mu;
  const float rstd = rsqrtf(var + 1e-5f);
  ushort4 o;
  o.x = f2b((v0 - mu) * rstd * g0 + e0);
  o.y = f2b((v1 - mu) * rstd * g1 + e1);
  o.z = f2b((v2 - mu) * rstd * g2 + e2);
  o.w = f2b((v3 - mu) * rstd * g3 + e3);
  *(ushort4*)(xn + base + t * 4) = o;
}

// ======== epilogue shared by both GEMMs (C/D layout col=lane&15, row=(lane>>4)*4+reg) ====
__device__ __forceinline__ void gemm_epilogue(
    f32x4 acc[4][4], int row0, int col0, int wm, int wn, int lane,
    const void* biasv, const void* residv, void* out,
    int N, float scale, int out_mode, int out_layout, int isbf) {
  const int colL = lane & 15;
  const int rq   = lane >> 4;
  const int wf32 = (out_mode == 1) || (out_mode == 2 && !isbf);
#pragma unroll
  for (int nt = 0; nt < 4; ++nt) {
    const int col = col0 + wn * 64 + nt * 16 + colL;
    if (col >= N) continue;
    const float bv = isbf ? b2f(((const unsigned short*)biasv)[col])
                          : ((const float*)biasv)[col];
#pragma unroll
    for (int mt = 0; mt < 4; ++mt) {
      const int rowb = row0 + wm * 64 + mt * 16 + rq * 4;
#pragma unroll
      for (int r = 0; r < 4; ++r) {
        const int row = rowb + r;
        size_t idx;
        if (out_layout == 1) {
          const int bb2 = row >> 12, t = row & 4095;           // L=4096
          idx = ((((size_t)bb2 * Hq + (col >> 4)) << 12) + t) * 16 + (col & 15);
        } else if (out_layout == 2) {
          const int bb2 = row >> 12, t = row & 4095;
          idx = (((size_t)bb2 * Hq + col) << 12) + t;
        } else {
          idx = (size_t)row * N + col;
        }
        float val = (acc[mt][nt][r] + bv) * scale;
        if (residv) {
          const size_t ridx = (size_t)row * N + col;           // resid always [M,N]
          val += isbf ? b2f(((const unsigned short*)residv)[ridx])
                      : ((const float*)residv)[ridx];
        }
        if (wf32) ((float*)out)[idx] = val;
        else ((unsigned short*)out)[idx] = f2b(val);
      }
    }
  }
}

// ---------------- MFMA GEMM (polymorphic W; reg-staged): gates + fallback path ----------
__global__ void gemm_bt(const unsigned short* __restrict__ A,
                        const void* __restrict__ Wv,
                        const void* __restrict__ biasv,
                        const void* __restrict__ residv,
                        void* __restrict__ out,
                        int N, int K, float scale, int out_mode, int out_layout,
                        const unsigned int* __restrict__ flagp) {
  __shared__ unsigned short smA[128 * 32];
  __shared__ unsigned short smB[128 * 32];
  const int isbf = (int)*flagp;
  const int tid  = threadIdx.x;
  const int w    = tid >> 6;
  const int lane = tid & 63;
  const int wm   = w >> 1;
  const int wn   = w & 1;
  const int row0 = blockIdx.x * 128;
  const int col0 = blockIdx.y * 128;

  const int c0 = tid, c1 = tid + 256;
  const int ar0 = row0 + (c0 >> 2), ak0 = (c0 & 3) * 8;
  const int ar1 = row0 + (c1 >> 2), ak1 = (c1 & 3) * 8;
  int br0 = col0 + (c0 >> 2), bk0 = (c0 & 3) * 8;
  int br1 = col0 + (c1 >> 2), bk1 = (c1 & 3) * 8;
  if (br0 >= N) br0 = N - 1;
  if (br1 >= N) br1 = N - 1;
  const size_t aro0 = (size_t)ar0 * K + ak0;
  const size_t aro1 = (size_t)ar1 * K + ak1;
  const size_t bro0 = (size_t)br0 * K + bk0;
  const size_t bro1 = (size_t)br1 * K + bk1;

  f32x4 acc[4][4];
#pragma unroll
  for (int i = 0; i < 4; ++i)
#pragma unroll
    for (int j = 0; j < 4; ++j) acc[i][j] = (f32x4){0.f, 0.f, 0.f, 0.f};

  const int mrow = lane & 15;
  const int kq8  = (lane >> 4) * 8;

  for (int k0 = 0; k0 < K; k0 += 32) {
    bf16x8 ta0 = *(const bf16x8*)(A + aro0 + k0);
    bf16x8 ta1 = *(const bf16x8*)(A + aro1 + k0);
    bf16x8 tb0, tb1;
    if (isbf) {
      const unsigned short* W = (const unsigned short*)Wv;
      tb0 = *(const bf16x8*)(W + bro0 + k0);
      tb1 = *(const bf16x8*)(W + bro1 + k0);
    } else {
      const float* W = (const float*)Wv;
      float4 w00 = *(const float4*)(W + bro0 + k0);
      float4 w01 = *(const float4*)(W + bro0 + k0 + 4);
      float4 w10 = *(const float4*)(W + bro1 + k0);
      float4 w11 = *(const float4*)(W + bro1 + k0 + 4);
      tb0 = pack8(w00, w01);
      tb1 = pack8(w10, w11);
    }
    __syncthreads();
    *(bf16x8*)(smA + c0 * 8) = ta0;
    *(bf16x8*)(smA + c1 * 8) = ta1;
    *(bf16x8*)(smB + c0 * 8) = tb0;
    *(bf16x8*)(smB + c1 * 8) = tb1;
    __syncthreads();
    bf16x8 a[4], bb[4];
#pragma unroll
    for (int mt = 0; mt < 4; ++mt)
      a[mt] = *(const bf16x8*)(smA + (wm * 64 + mt * 16 + mrow) * 32 + kq8);
#pragma unroll
    for (int nt = 0; nt < 4; ++nt)
      bb[nt] = *(const bf16x8*)(smB + (wn * 64 + nt * 16 + mrow) * 32 + kq8);
#pragma unroll
    for (int mt = 0; mt < 4; ++mt)
#pragma unroll
      for (int nt = 0; nt < 4; ++nt)
        acc[mt][nt] = __builtin_amdgcn_mfma_f32_16x16x32_bf16(a[mt], bb[nt], acc[mt][nt], 0, 0, 0);
  }
  gemm_epilogue(acc, row0, col0, wm, wn, lane, biasv, residv, out,
                N, scale, out_mode, out_layout, isbf);
}

// ---------------- fast MFMA GEMM: bf16 A and W, global_load_lds staging (m97) ----------
// N == K == Dq fixed. W must be pre-converted bf16 [N][K].
// 1-D grid of 2048 with XCD-chunked decode: each XCD owns 32 contiguous row-panels
// and walks the 8 column tiles of a panel back-to-back -> A-panel L2-resident, A
// fetched from HBM once per GEMM (was 8x with the (row,col) 2-D grid).
__global__ void __launch_bounds__(256)
gemm16(const unsigned short* __restrict__ A,
       const unsigned short* __restrict__ W,
       const void* __restrict__ biasv,
       const void* __restrict__ residv,
       void* __restrict__ out,
       float scale, int out_mode, int out_layout,
       const unsigned int* __restrict__ flagp) {
  __shared__ unsigned short smA[128 * 32];
  __shared__ unsigned short smB[128 * 32];
  const int isbf = (int)*flagp;
  const int tid  = threadIdx.x;
  const int w    = tid >> 6;
  const int lane = tid & 63;
  const int wm   = w >> 1;
  const int wn   = w & 1;
  // XCD-chunked panel decode (2048 = 8 xcd * 32 row-panels * 8 col-tiles)
  const int o    = blockIdx.x;
  const int xcd  = o & 7;
  const int slot = o >> 3;
  const int rloc = slot >> 3;        // 0..31, row-panel within xcd
  const int cloc = slot & 7;         // 0..7, col tile (fastest within xcd)
  const int row0 = (xcd * 32 + rloc) * 128;
  const int col0 = cloc * 128;

  // staging: wave w stages chunks {2w, 2w+1}; chunk c = 16 rows; lane covers
  // row = c*16 + (lane>>2), k8 = (lane&3)*8.  LDS dest wave-uniform: chunk base.
  const int rA0 = (w * 2) * 16 + (lane >> 2);
  const size_t aoff0 = (size_t)(row0 + rA0) * Dq + (lane & 3) * 8;
  const size_t aoff1 = aoff0 + (size_t)16 * Dq;
  const size_t boff0 = (size_t)(col0 + rA0) * Dq + (lane & 3) * 8;
  const size_t boff1 = boff0 + (size_t)16 * Dq;
  unsigned short* ldsA0 = smA + w * 1024;        // chunk 2w   (512 ushorts = 1 KiB)
  unsigned short* ldsA1 = smA + w * 1024 + 512;  // chunk 2w+1
  unsigned short* ldsB0 = smB + w * 1024;
  unsigned short* ldsB1 = smB + w * 1024 + 512;

  f32x4 acc[4][4];
#pragma unroll
  for (int i = 0; i < 4; ++i)
#pragma unroll
    for (int j = 0; j < 4; ++j) acc[i][j] = (f32x4){0.f, 0.f, 0.f, 0.f};

  const int mrow = lane & 15;
  const int kq8  = (lane >> 4) * 8;

  for (int k0 = 0; k0 < Dq; k0 += 32) {
    __syncthreads();   // prev iteration's ds_reads done before overwrite
    gload_lds16(A + aoff0 + k0, ldsA0);
    gload_lds16(A + aoff1 + k0, ldsA1);
    gload_lds16(W + boff0 + k0, ldsB0);
    gload_lds16(W + boff1 + k0, ldsB1);
    __syncthreads();   // compiler drains vmcnt(0) before barrier -> tiles ready
    bf16x8 a[4], bb[4];
#pragma unroll
    for (int mt = 0; mt < 4; ++mt)
      a[mt] = *(const bf16x8*)(smA + (wm * 64 + mt * 16 + mrow) * 32 + kq8);
#pragma unroll
    for (int nt = 0; nt < 4; ++nt)
      bb[nt] = *(const bf16x8*)(smB + (wn * 64 + nt * 16 + mrow) * 32 + kq8);
#pragma unroll
    for (int mt = 0; mt < 4; ++mt)
#pragma unroll
      for (int nt = 0; nt < 4; ++nt)
        acc[mt][nt] = __builtin_amdgcn_mfma_f32_16x16x32_bf16(a[mt], bb[nt], acc[mt][nt], 0, 0, 0);
  }
  gemm_epilogue(acc, row0, col0, wm, wn, lane, biasv, residv, out,
                Dq, scale, out_mode, out_layout, isbf);
}

// ---------------- shared helper: bf16x16 row -> f32 LDS row with quad swizzle ----------
__device__ __forceinline__ void deposit16(float* __restrict__ dstrow, int xw,
                                          bf16x8 lo, bf16x8 hi) {
  float t[16];
#pragma unroll
  for (int j = 0; j < 8; ++j) t[j] = b2f((unsigned short)lo[j]);
#pragma unroll
  for (int j = 0; j < 8; ++j) t[8 + j] = b2f((unsigned short)hi[j]);
#pragma unroll
  for (int qd = 0; qd < 4; ++qd) {
    *(float4*)(dstrow + ((qd << 2) ^ xw)) =
        make_float4(t[qd * 4], t[qd * 4 + 1], t[qd * 4 + 2], t[qd * 4 + 3]);
  }
}

// =================== chunked-parallel mLSTM scan ===================
// Decomposition: F_t = prefix-sum(f), w_s = i_s - F_s, m_t = F_t + max(m_in, max_{s<=t} w_s)
//   C_t = exp(m_in + F_t - m_t) C_in + exp(F_t - m_t) sum_{s<=t} exp(w_s) v_s k_s^T
// Record layout (f32, per chunk, stride RECF): [e*16+d] C_{d,e}; [256+d] n_d; [272] Ml/m_in; [273] F.

// Pass 1: per-chunk summaries via MFMA.  G[d][e] = sum_s (p_s v_s[d]) k_s[e] is a
// 16x16 (K=64) matmul: A row d = (p .* V)^T, B row e = K^T (operands-as-rows, same
// convention as gemm_bt).  The p*v product is split hi/lo into two bf16 fragments so
// the result matches the old f32 FMA chain to ~2^-17.  C/D layout (col=lane&15=e,
// row=(lane>>4)*4+r=d) maps exactly onto the record's rec[e*16+d] convention.
__global__ void __launch_bounds__(64, 1)
summary_kernel(const unsigned short* __restrict__ k,
               const unsigned short* __restrict__ v,
               const float* __restrict__ itg,
               const float* __restrict__ ftg,
               float* __restrict__ sum) {
  __shared__ unsigned short skb[CH * 16];   // K bf16 [s][e]
  __shared__ unsigned short svb[CH * 16];   // V bf16 [s][d]
  __shared__ float sp[CH];
  const int bid = blockIdx.x;
  const int bh  = bid >> 6;            // NC == 64
  const int c   = bid & 63;
  const int lane = threadIdx.x;
  const size_t qkvb = ((size_t)bh * Lq + (size_t)c * CH) * 16;
  const size_t gb   = (size_t)bh * Lq + (size_t)c * CH;

  // per-lane gates; lane index == local timestep
  float fv = ftg[gb + lane];
  float iv = itg[gb + lane];
  // inclusive prefix-sum of f across the wave
  float F = fv;
#pragma unroll
  for (int off = 1; off < 64; off <<= 1) {
    float tt = __shfl_up(F, off, 64);
    if (lane >= off) F += tt;
  }
  float wv = iv - F;
  float Ml = wv;
#pragma unroll
  for (int off = 1; off < 64; off <<= 1)
    Ml = fmaxf(Ml, __shfl_xor(Ml, off, 64));
  const float Ftot = __shfl(F, 63, 64);

  // stage raw bf16 K,V tiles + p
  {
    const unsigned short* kp = k + qkvb + (size_t)lane * 16;
    const unsigned short* vp = v + qkvb + (size_t)lane * 16;
    *(bf16x8*)(skb + lane * 16)     = *(const bf16x8*)kp;
    *(bf16x8*)(skb + lane * 16 + 8) = *(const bf16x8*)(kp + 8);
    *(bf16x8*)(svb + lane * 16)     = *(const bf16x8*)vp;
    *(bf16x8*)(svb + lane * 16 + 8) = *(const bf16x8*)(vp + 8);
    sp[lane] = __expf(wv - Ml);   // p_s in (0,1]
  }
  // single wave: DS ops in-order, compiler inserts lgkmcnt (same as chunk_scan)

  const int e  = lane & 15;            // e for B/n, d for A (both = lane&15 by spec)
  const int sg = lane >> 4;

  // n_d = sum_s p_s K[s][d]  (VALU: 16 FMA + 2 shuffles)
  float nacc = 0.f;
#pragma unroll
  for (int j = 0; j < 16; ++j) {
    const int s = sg * 16 + j;
    nacc = fmaf(sp[s], b2f(skb[s * 16 + e]), nacc);
  }
  nacc += __shfl_xor(nacc, 16, 64);
  nacc += __shfl_xor(nacc, 32, 64);

  // G via MFMA, hi/lo split on the p*v operand
  f32x4 acc = (f32x4){0.f, 0.f, 0.f, 0.f};
#pragma unroll
  for (int kk = 0; kk < 2; ++kk) {
    bf16x8 ahi, alo, bfr;
#pragma unroll
    for (int j = 0; j < 8; ++j) {
      const int s = kk * 32 + sg * 8 + j;
      const float pv = sp[s] * b2f(svb[s * 16 + e]);
      const unsigned short hi = f2b(pv);
      ahi[j] = (short)hi;
      alo[j] = (short)f2b(pv - b2f(hi));
      bfr[j] = (short)skb[s * 16 + e];
    }
    acc = __builtin_amdgcn_mfma_f32_16x16x32_bf16(ahi, bfr, acc, 0, 0, 0);
    acc = __builtin_amdgcn_mfma_f32_16x16x32_bf16(alo, bfr, acc, 0, 0, 0);
  }

  float* rec = sum + (size_t)bid * RECF;
  *(f32x4*)(rec + e * 16 + sg * 4) = acc;     // G[d=sg*4+r][e]
  if (sg == 0) rec[256 + e] = nacc;           // n_d, d = lane (0..15)
  if (lane == 0) { rec[272] = Ml; rec[273] = Ftot; }
}

// Pass 2: sequential combine over chunks per (b,h); rewrites each record with the
// INCOMING (chunk-start) state in place.
__global__ void __launch_bounds__(64, 1)
combine_kernel(float* __restrict__ sum) {
  const int bh = blockIdx.x;
  const int lane = threadIdx.x;
  float* base = sum + (size_t)bh * NC * RECF;
  float4 Sc = make_float4(0.f, 0.f, 0.f, 0.f);
  float Sn = 0.f;
  float m = 0.f;
  // prefetch chunk 0
  float4 G = *(float4*)(base + lane * 4);
  float gn = (lane < 16) ? base[256 + lane] : 0.f;
  float Ml = base[272], F = base[273];
  for (int c = 0; c < NC; ++c) {
    float* rec = base + (size_t)c * RECF;
    float4 Gn = make_float4(0.f, 0.f, 0.f, 0.f);
    float gnn = 0.f, Mln = 0.f, Fn = 0.f;
    if (c + 1 < NC) {
      float* rn = rec + RECF;
      Gn = *(float4*)(rn + lane * 4);
      if (lane < 16) gnn = rn[256 + lane];
      Mln = rn[272]; Fn = rn[273];
    }
    // store the incoming state over the record
    *(float4*)(rec + lane * 4) = Sc;
    if (lane < 16) rec[256 + lane] = Sn;
    if (lane == 0) rec[272] = m;
    // state update (all stabilized exps <= 1)
    const float mx = fmaxf(m, Ml);
    const float al = __expf(m - mx);
    const float be = __expf(Ml - mx);
    Sc.x = fmaf(al, Sc.x, be * G.x);
    Sc.y = fmaf(al, Sc.y, be * G.y);
    Sc.z = fmaf(al, Sc.z, be * G.z);
    Sc.w = fmaf(al, Sc.w, be * G.w);
    Sn = fmaf(al, Sn, be * gn);
    m = F + mx;
    G = Gn; gn = gnn; Ml = Mln; F = Fn;
  }
}

// Pass 3: per-chunk sequential scan seeded from the stored chunk-start state.
__global__ void __launch_bounds__(64, 1)
chunk_scan_kernel(const unsigned short* __restrict__ q,
                  const unsigned short* __restrict__ k,
                  const unsigned short* __restrict__ v,
                  const float* __restrict__ itg,
                  const float* __restrict__ ftg,
                  const float* __restrict__ sum,
                  unsigned short* __restrict__ hout) {
  __shared__ float sk[CH * 16], sq[CH * 16], sv[CH * 16], sg[2 * CH];
  const int bid = blockIdx.x;
  const int bh  = bid >> 6;
  const int c   = bid & 63;
  const int b   = bh >> 6;
  const int h   = bh & 63;
  const int lane = threadIdx.x;
  const int e  = lane & 15;
  const int dg = lane >> 4;
  const int d0 = dg * 4;
  const size_t qkvb = ((size_t)bh * Lq + (size_t)c * CH) * 16;
  const size_t gb   = (size_t)bh * Lq + (size_t)c * CH;
  const size_t ob   = (size_t)b * Lq * Dq + (size_t)h * 16 + (size_t)c * CH * Dq;

  // load chunk-start state
  const float* rec = sum + (size_t)bid * RECF;
  const float4 Cv = *(const float4*)(rec + e * 16 + d0);
  const float4 nv = *(const float4*)(rec + 256 + d0);
  float m = rec[272];
  float C0 = Cv.x, C1 = Cv.y, C2 = Cv.z, C3 = Cv.w;
  float n0 = nv.x, n1 = nv.y, n2 = nv.z, n3 = nv.w;

  // stage the chunk tile
  const int xw = ((lane >> 1) & 3) << 2;
  {
    const unsigned short* kp = k + qkvb + (size_t)lane * 16;
    const unsigned short* qp = q + qkvb + (size_t)lane * 16;
    const unsigned short* vp = v + qkvb + (size_t)lane * 16;
    bf16x8 a0 = *(const bf16x8*)kp, a1 = *(const bf16x8*)(kp + 8);
    bf16x8 b0 = *(const bf16x8*)qp, b1 = *(const bf16x8*)(qp + 8);
    bf16x8 c0v = *(const bf16x8*)vp, c1v = *(const bf16x8*)(vp + 8);
    deposit16(sk + lane * 16, xw, a0, a1);
    deposit16(sq + lane * 16, xw, b0, b1);
    deposit16(sv + lane * 16, xw, c0v, c1v);
    sg[lane] = itg[gb + lane];
    sg[CH + lane] = ftg[gb + lane];
  }

#pragma unroll 4
  for (int s = 0; s < CH; ++s) {
    const int x = ((s >> 1) & 3) << 2;
    const float* kr = sk + s * 16;
    const float* qr = sq + s * 16;
    const float* vr = sv + s * 16;
    const float itc = sg[s];
    const float ftc = sg[CH + s];
    const float ke  = kr[e ^ x];
    const float4 kq4 = *(const float4*)(kr + (d0 ^ x));
    const float4 qq4 = *(const float4*)(qr + (d0 ^ x));
    const float4 vq4 = *(const float4*)(vr + (d0 ^ x));
    const float fm = ftc + m;
    const float mn = fmaxf(fm, itc);
    const float fg = __expf(fm - mn);   // <= 1
    const float ig = __expf(itc - mn);  // <= 1
    m = mn;
    const float a = ig * ke;
    C0 = fmaf(fg, C0, a * vq4.x);
    C1 = fmaf(fg, C1, a * vq4.y);
    C2 = fmaf(fg, C2, a * vq4.z);
    C3 = fmaf(fg, C3, a * vq4.w);
    n0 = fmaf(fg, n0, ig * kq4.x);
    n1 = fmaf(fg, n1, ig * kq4.y);
    n2 = fmaf(fg, n2, ig * kq4.z);
    n3 = fmaf(fg, n3, ig * kq4.w);
    float cq = fmaf(C3, qq4.w, fmaf(C2, qq4.z, fmaf(C1, qq4.y, C0 * qq4.x)));
    float dn = fmaf(n3, qq4.w, fmaf(n2, qq4.z, fmaf(n1, qq4.y, n0 * qq4.x)));
    cq += __shfl_xor(cq, 16, 64);
    cq += __shfl_xor(cq, 32, 64);
    dn += __shfl_xor(dn, 16, 64);
    dn += __shfl_xor(dn, 32, 64);
    const float denom = fmaxf(fabsf(dn), 1.0f);
    if (dg == 0) hout[ob + (size_t)s * Dq + e] = f2b(cq / denom);
  }
}

// ---------------- fallback: monolithic tiled scan (round-1, proven) ----------------
__global__ void __launch_bounds__(64, 1)
scan_kernel(const unsigned short* __restrict__ q,
            const unsigned short* __restrict__ k,
            const unsigned short* __restrict__ v,
            const float* __restrict__ itg,
            const float* __restrict__ ftg,
            unsigned short* __restrict__ hout) {
  __shared__ float sk[CH * 16], sq[CH * 16], sv[CH * 16], sg[2 * CH];
  const int bh = blockIdx.x;
  const int b  = bh >> 6;
  const int h  = bh & 63;
  const int lane = threadIdx.x;
  const int e  = lane & 15;
  const int dg = lane >> 4;
  const int d0 = dg * 4;
  const size_t qkvb = (size_t)bh * Lq * 16;
  const size_t gb   = (size_t)bh * Lq;
  const size_t ob   = (size_t)b * Lq * Dq + (size_t)h * 16;

  float C0 = 0, C1 = 0, C2 = 0, C3 = 0;
  float n0 = 0, n1 = 0, n2 = 0, n3 = 0;
  float m = 0.f;

  bf16x8 rk0, rk1, rq0, rq1, rv0, rv1;
  float rit, rft;
  {
    const unsigned short* kp = k + qkvb + (size_t)lane * 16;
    const unsigned short* qp = q + qkvb + (size_t)lane * 16;
    const unsigned short* vp = v + qkvb + (size_t)lane * 16;
    rk0 = *(const bf16x8*)kp; rk1 = *(const bf16x8*)(kp + 8);
    rq0 = *(const bf16x8*)qp; rq1 = *(const bf16x8*)(qp + 8);
    rv0 = *(const bf16x8*)vp; rv1 = *(const bf16x8*)(vp + 8);
    rit = itg[gb + lane]; rft = ftg[gb + lane];
  }

  const int xw = ((lane >> 1) & 3) << 2;
  const int NT = Lq / CH;
  for (int c = 0; c < NT; ++c) {
    deposit16(sk + lane * 16, xw, rk0, rk1);
    deposit16(sq + lane * 16, xw, rq0, rq1);
    deposit16(sv + lane * 16, xw, rv0, rv1);
    sg[lane] = rit; sg[CH + lane] = rft;
    if (c + 1 < NT) {
      const size_t off = qkvb + ((size_t)(c + 1) * CH + lane) * 16;
      const unsigned short* kp = k + off;
      const unsigned short* qp = q + off;
      const unsigned short* vp = v + off;
      rk0 = *(const bf16x8*)kp; rk1 = *(const bf16x8*)(kp + 8);
      rq0 = *(const bf16x8*)qp; rq1 = *(const bf16x8*)(qp + 8);
      rv0 = *(const bf16x8*)vp; rv1 = *(const bf16x8*)(vp + 8);
      rit = itg[gb + (size_t)(c + 1) * CH + lane];
      rft = ftg[gb + (size_t)(c + 1) * CH + lane];
    }
#pragma unroll 4
    for (int s = 0; s < CH; ++s) {
      const int x = ((s >> 1) & 3) << 2;
      const float* kr = sk + s * 16;
      const float* qr = sq + s * 16;
      const float* vr = sv + s * 16;
      const float itc = sg[s];
      const float ftc = sg[CH + s];
      const float ke  = kr[e ^ x];
      const float4 kq4 = *(const float4*)(kr + (d0 ^ x));
      const float4 qq4 = *(const float4*)(qr + (d0 ^ x));
      const float4 vq4 = *(const float4*)(vr + (d0 ^ x));
      const float fm = ftc + m;
      const float mn = fmaxf(fm, itc);
      const float fg = __expf(fm - mn);
      const float ig = __expf(itc - mn);
      m = mn;
      const float a = ig * ke;
      C0 = fmaf(fg, C0, a * vq4.x);
      C1 = fmaf(fg, C1, a * vq4.y);
      C2 = fmaf(fg, C2, a * vq4.z);
      C3 = fmaf(fg, C3, a * vq4.w);
      n0 = fmaf(fg, n0, ig * kq4.x);
      n1 = fmaf(fg, n1, ig * kq4.y);
      n2 = fmaf(fg, n2, ig * kq4.z);
      n3 = fmaf(fg, n3, ig * kq4.w);
      float cq = fmaf(C3, qq4.w, fmaf(C2, qq4.z, fmaf(C1, qq4.y, C0 * qq4.x)));
      float dn = fmaf(n3, qq4.w, fmaf(n2, qq4.z, fmaf(n1, qq4.y, n0 * qq4.x)));
      cq += __shfl_xor(cq, 16, 64);
      cq += __shfl_xor(cq, 32, 64);
      dn += __shfl_xor(dn, 16, 64);
      dn += __shfl_xor(dn, 32, 64);
      const float denom = fmaxf(fabsf(dn), 1.0f);
      if (dg == 0) hout[ob + (size_t)(c * CH + s) * Dq + e] = f2b(cq / denom);
    }
  }
}

extern "C" void kernel_launch(void* const* d_in, const int* in_sizes, int n_in,
                              void* d_out, int out_size, void* d_ws, size_t ws_size,
                              hipStream_t stream) {
  const void* x     = d_in[0];
  const void* gamma = d_in[1];
  const void* beta  = d_in[2];
  const void* qw    = d_in[3];
  const void* qbv   = d_in[4];
  const void* kw    = d_in[5];
  const void* kbv   = d_in[6];
  const void* vw    = d_in[7];
  const void* vbv   = d_in[8];
  const void* ow    = d_in[9];
  const void* obv   = d_in[10];
  const void* iw    = d_in[11];
  const void* ibv   = d_in[12];
  const void* fw    = d_in[13];
  const void* fbv   = d_in[14];

  const size_t bufBytes  = (size_t)Mq * Dq * 2;        // 64 MiB
  const size_t gateBytes = (size_t)Mq * Hq * 4;        // 8 MiB
  const size_t sumBytes  = (size_t)TC * RECF * 4;      // ~37.75 MiB
  const size_t wBytes    = (size_t)Dq * Dq * 2;        // 2 MiB per converted weight
  const size_t need_old   = 4 * bufBytes + 2 * gateBytes + 4096;
  const size_t need_chunk = need_old + sumBytes;
  const size_t need_fast  = need_chunk + 4 * wBytes;
  if (ws_size < need_old) {   // diagnostic: absmax ~= 1000 signals this branch
    sentinel_kernel<<<(out_size + 255) / 256, 256, 0, stream>>>((unsigned short*)d_out, out_size);
    return;
  }
  const int chunked = (ws_size >= need_chunk);
  const int fast    = (ws_size >= need_fast);

  char* ws = (char*)d_ws;
  unsigned short* xnb = (unsigned short*)ws; ws += bufBytes;   // reused as hbf
  unsigned short* qbf = (unsigned short*)ws; ws += bufBytes;
  unsigned short* kbf = (unsigned short*)ws; ws += bufBytes;
  unsigned short* vbf = (unsigned short*)ws; ws += bufBytes;
  float* itb = (float*)ws; ws += gateBytes;
  float* ftb = (float*)ws; ws += gateBytes;
  unsigned int* flagp = (unsigned int*)ws; ws += 4096;
  float* sumb = (float*)ws; ws += sumBytes;
  unsigned short* wqb = (unsigned short*)ws; ws += wBytes;
  unsigned short* wkb = (unsigned short*)ws; ws += wBytes;
  unsigned short* wvb = (unsigned short*)ws; ws += wBytes;
  unsigned short* wob = (unsigned short*)ws; ws += wBytes;
  unsigned short* hbf = xnb;  // alias: xn dead after the 5 projection GEMMs

  classify_kernel<<<1, 256, 0, stream>>>((const unsigned short*)qw, flagp);
  ln_kernel<<<Mq, 256, 0, stream>>>(x, gamma, beta, xnb, flagp);
  // q/k/v -> [B,H,L,16] bf16 (layout 1); gates -> [B,H,L] f32 (layout 2)
  if (fast) {
    const int wgrid = (Dq * Dq / 8) / 256;   // 512 blocks
    wconv_kernel<<<wgrid, 256, 0, stream>>>(qw, wqb, flagp);
    wconv_kernel<<<wgrid, 256, 0, stream>>>(kw, wkb, flagp);
    wconv_kernel<<<wgrid, 256, 0, stream>>>(vw, wvb, flagp);
    wconv_kernel<<<wgrid, 256, 0, stream>>>(ow, wob, flagp);
    gemm16<<<dim3(2048), 256, 0, stream>>>(xnb, wqb, qbv, nullptr, qbf, 1.0f,  0, 1, flagp);
    gemm16<<<dim3(2048), 256, 0, stream>>>(xnb, wkb, kbv, nullptr, kbf, 0.25f, 0, 1, flagp); // /sqrt(16)
    gemm16<<<dim3(2048), 256, 0, stream>>>(xnb, wvb, vbv, nullptr, vbf, 1.0f,  0, 1, flagp);
  } else {
    gemm_bt<<<dim3(Mq / 128, 8), 256, 0, stream>>>(xnb, qw, qbv, nullptr, qbf, Dq, Dq, 1.0f,  0, 1, flagp);
    gemm_bt<<<dim3(Mq / 128, 8), 256, 0, stream>>>(xnb, kw, kbv, nullptr, kbf, Dq, Dq, 0.25f, 0, 1, flagp);
    gemm_bt<<<dim3(Mq / 128, 8), 256, 0, stream>>>(xnb, vw, vbv, nullptr, vbf, Dq, Dq, 1.0f,  0, 1, flagp);
  }
  gemm_bt<<<dim3(Mq / 128, 1), 256, 0, stream>>>(xnb, iw, ibv, nullptr, itb, Hq, Dq, 1.0f,  1, 2, flagp);
  gemm_bt<<<dim3(Mq / 128, 1), 256, 0, stream>>>(xnb, fw, fbv, nullptr, ftb, Hq, Dq, 1.0f,  1, 2, flagp);
  if (chunked) {
    summary_kernel<<<TC, 64, 0, stream>>>(kbf, vbf, itb, ftb, sumb);
    combine_kernel<<<Bq * Hq, 64, 0, stream>>>(sumb);
    chunk_scan_kernel<<<TC, 64, 0, stream>>>(qbf, kbf, vbf, itb, ftb, sumb, hbf);
  } else {
    scan_kernel<<<Bq * Hq, 64, 0, stream>>>(qbf, kbf, vbf, itb, ftb, hbf);
  }
  if (fast) {
    gemm16<<<dim3(2048), 256, 0, stream>>>(hbf, wob, obv, x, d_out, 1.0f, 2, 0, flagp);
  } else {
    gemm_bt<<<dim3(Mq / 128, 8), 256, 0, stream>>>(hbf, ow, obv, x, d_out, Dq, Dq, 1.0f, 2, 0, flagp);
  }
}